// Round 12
// baseline (1252.693 us; speedup 1.0000x reference)
//
#include <hip/hip_runtime.h>
#include <hip/hip_fp16.h>

typedef _Float16 f16;
typedef _Float16 f16x4 __attribute__((ext_vector_type(4)));
typedef _Float16 f16x8 __attribute__((ext_vector_type(8)));
typedef float f32x4 __attribute__((ext_vector_type(4)));
typedef int i32x4 __attribute__((ext_vector_type(4)));

#define MFMA16(a, b, c) __builtin_amdgcn_mfma_f32_16x16x32_f16((a), (b), (c), 0, 0, 0)
#define MFMAI8(a, b, c) __builtin_amdgcn_mfma_i32_16x16x64_i8((a), (b), (c), 0, 0, 0)

#define FLAG_CAP (1024 * 1024)
#define FLAG_TOL 1e-3f

#define SBAR()   __builtin_amdgcn_s_barrier()
#define SCHEDB() __builtin_amdgcn_sched_barrier(0)

// async global->LDS, 16 B per lane. LDS dest is wave-uniform base (+lane*16);
// global src is per-lane (swizzle baked into source address).
__device__ __forceinline__ void gld16(const void* g, void* l) {
    __builtin_amdgcn_global_load_lds(
        (const __attribute__((address_space(1))) unsigned int*)g,
        (__attribute__((address_space(3))) unsigned int*)l,
        16, 0, 0);
}

// ---------------- scale computation ----------------

__global__ void k_zero(float* p, int* cnt) {
    if (threadIdx.x < 3) p[threadIdx.x] = 0.f;
    if (threadIdx.x == 3) { cnt[0] = 0; cnt[1] = 0; }
}

__global__ void k_absmax(const float* __restrict__ w, int n, float* __restrict__ out) {
    float m = 0.f;
    int stride = gridDim.x * blockDim.x;
    for (int i = blockIdx.x * blockDim.x + threadIdx.x; i < n; i += stride)
        m = fmaxf(m, fabsf(w[i]));
    #pragma unroll
    for (int o = 32; o > 0; o >>= 1) m = fmaxf(m, __shfl_down(m, o));
    __shared__ float sm[4];
    int lane = threadIdx.x & 63, wv = threadIdx.x >> 6;
    if (lane == 0) sm[wv] = m;
    __syncthreads();
    if (threadIdx.x == 0) {
        float mm = fmaxf(fmaxf(sm[0], sm[1]), fmaxf(sm[2], sm[3]));
        atomicMax((unsigned int*)out, __float_as_uint(mm));  // nonneg floats only
    }
}

// W1: fp32 dequant w1dq (fixup) + padded f16 panel q1h [512][832]
__global__ void k_quantw1(const float* __restrict__ w, const float* __restrict__ wmax,
                          float* __restrict__ wdq, f16* __restrict__ q1h) {
    int i = blockIdx.x * blockDim.x + threadIdx.x;
    if (i >= 512 * 832) return;
    int n = i / 832, k = i - n * 832;
    float v = 0.f;
    if (k < 784) {
        float s = wmax[0] / 7.0f + 1e-8f;
        v = rintf(w[n * 784 + k] / s);       // fp32 ops replicate numpy semantics
        v = fminf(fmaxf(v, -7.f), 7.f);
        wdq[n * 784 + k] = v * s;
    }
    q1h[(size_t)n * 832 + k] = (f16)v;
}

// W2: int8 codes + fp32 dequant (fixup)
__global__ void k_quantw2(const float* __restrict__ w, const float* __restrict__ wmax,
                          signed char* __restrict__ q, float* __restrict__ wdq, int n) {
    float s = wmax[0] / 7.0f + 1e-8f;
    int i = blockIdx.x * blockDim.x + threadIdx.x;
    if (i < n) {
        float v = rintf(w[i] / s);
        v = fminf(fmaxf(v, -7.f), 7.f);
        q[i] = (signed char)v;
        if (wdq) wdq[i] = v * s;
    }
}

// W3: int8, zero-padded to 16x512
__global__ void k_quantw3(const float* __restrict__ w, const float* __restrict__ wmax,
                          signed char* __restrict__ q) {
    float s = wmax[0] / 7.0f + 1e-8f;
    int i = blockIdx.x * blockDim.x + threadIdx.x;
    if (i < 16 * 512) {
        float v = 0.f;
        if (i < 10 * 512) {
            v = rintf(w[i] / s);
            v = fminf(fmaxf(v, -7.f), 7.f);
        }
        q[i] = (signed char)v;
    }
}

// ========== GEMM1: full-N block (128 x 512), K=832, BK=32 ==========
// Every wait references loads issued ONE FULL ITERATION earlier (latency hidden
// by compute+barrier, ~900cy). LDS = 80KB -> 2 blocks/CU (TLP covers the rest).
// LDS rows are 64B; element (r, 16B-slot s) stored at slot s^((r>>1)&3) -> 2-way
// banks (free). Write-side swizzle via global source (B) / ds_write addr (A).

__global__ __launch_bounds__(512, 4) void k_gemm1G(
    const float* __restrict__ X, const f16* __restrict__ B,
    const float* __restrict__ wmax, const float* __restrict__ s1p,
    signed char* __restrict__ A1, int* __restrict__ flagCnt, unsigned* __restrict__ flagList)
{
    constexpr int NT = 26;                       // 832/32 K-tiles
    __shared__ __align__(16) f16 Bt[2][512 * 32];    // 64 KB
    __shared__ __align__(16) f16 Ah[128 * 32];       // 8 KB
    __shared__ __align__(16) f16 Al[128 * 32];       // 8 KB

    const int t = threadIdx.x;
    const int lane = t & 63, w = t >> 6;
    const int wr = w >> 2, wc = w & 3;           // 2x4 wave grid; wave tile 64x128
    const int l15 = lane & 15, l4 = lane >> 4;
    const int row0 = blockIdx.x * 128;

    f32x4 acc[4][8];
    #pragma unroll
    for (int m = 0; m < 4; ++m)
        #pragma unroll
        for (int n = 0; n < 8; ++n) acc[m][n] = (f32x4){0.f, 0.f, 0.f, 0.f};

    // B staging map: chunk = 16 rows x 32 cols; lane -> (lr=lane>>2, slot=lane&3)
    // global src col-slot = slot ^ ((lr>>1)&3) so linear LDS holds swizzled layout
    const int blr = lane >> 2;
    const int bslot = (lane & 3) ^ ((lane >> 3) & 3);
    const f16* Bb = B + (size_t)blr * 832 + bslot * 8;

    // X (A) reg staging: thread covers 2 float4 of the 128x32 tile
    float4 av[2];
    auto LOADA = [&](int tn) {
        #pragma unroll
        for (int i = 0; i < 2; ++i) {
            int f = t + 512 * i;
            int r = f >> 3, s = f & 7;           // r:0..127, s: float4 slot 0..7
            int gk = tn * 32 + s * 4;
            av[i] = make_float4(0.f, 0.f, 0.f, 0.f);
            if (gk < 784)
                av[i] = *reinterpret_cast<const float4*>(X + (size_t)(row0 + r) * 784 + gk);
        }
    };
    // split av -> hi/lo, swizzled ds_write (8B halves of 16B slots)
    auto WRITEA = [&]() {
        #pragma unroll
        for (int i = 0; i < 2; ++i) {
            int f = t + 512 * i;
            int r = f >> 3, s = f & 7;
            float vv[4] = {av[i].x, av[i].y, av[i].z, av[i].w};
            f16x4 h0, h1;
            #pragma unroll
            for (int j = 0; j < 4; ++j) {
                f16 c0 = (f16)vv[j];                 // RNE
                h0[j] = c0;
                h1[j] = (f16)(vv[j] - (float)c0);    // exact residual
            }
            int slot = (s >> 1) ^ ((r >> 1) & 3);
            int ad = r * 32 + slot * 8 + (s & 1) * 4;   // f16 units
            *reinterpret_cast<f16x4*>(&Ah[ad]) = h0;
            *reinterpret_cast<f16x4*>(&Al[ad]) = h1;
        }
    };

    // prologue: issue B(0), X(0)
    {
        #pragma unroll
        for (int i = 0; i < 4; ++i) {
            int ch = w * 4 + i;                  // 32 chunks x 16 rows = 512
            gld16(Bb + (size_t)ch * 16 * 832, &Bt[0][ch * 512]);
        }
        LOADA(0);
    }

    int cur = 0;
    for (int tt = 0; tt < NT; ++tt) {
        asm volatile("s_waitcnt vmcnt(0)" ::: "memory");  // B(tt), X(tt) landed (issued 1 iter ago)
        SBAR();                                  // all waves: loads landed, done compute(tt-1)
        WRITEA();                                // A(tt) -> LDS
        if (tt + 1 < NT) {                       // issue next tile's loads (land under compute)
            #pragma unroll
            for (int i = 0; i < 4; ++i) {
                int ch = w * 4 + i;
                gld16(Bb + (size_t)ch * 16 * 832 + (tt + 1) * 32, &Bt[cur ^ 1][ch * 512]);
            }
            LOADA(tt + 1);
        }
        SCHEDB();
        asm volatile("s_waitcnt lgkmcnt(0)" ::: "memory");  // my A ds_writes done
        SBAR();                                  // A(tt) visible to all; B(tt) ready

        // one K=32 step: 8 A-frag reads (hi+lo), 8 B-frag reads, 64 MFMA
        {
            f16x8 fh[4], fl_[4], bf[8];
            #pragma unroll
            for (int m = 0; m < 4; ++m) {
                int row = wr * 64 + m * 16 + l15;
                int ad = row * 32 + ((l4 ^ ((row >> 1) & 3)) * 8);
                fh[m]  = *reinterpret_cast<const f16x8*>(&Ah[ad]);
                fl_[m] = *reinterpret_cast<const f16x8*>(&Al[ad]);
            }
            #pragma unroll
            for (int n = 0; n < 8; ++n) {
                int row = wc * 128 + n * 16 + l15;
                int ad = row * 32 + ((l4 ^ ((row >> 1) & 3)) * 8);
                bf[n] = *reinterpret_cast<const f16x8*>(&Bt[cur][ad]);
            }
            #pragma unroll
            for (int m = 0; m < 4; ++m)
                #pragma unroll
                for (int n = 0; n < 8; ++n) {
                    acc[m][n] = MFMA16(fh[m],  bf[n], acc[m][n]);
                    acc[m][n] = MFMA16(fl_[m], bf[n], acc[m][n]);
                }
        }
        cur ^= 1;
    }

    float sw = wmax[0] / 7.0f + 1e-8f;
    float s1v = s1p[0];
    #pragma unroll
    for (int m = 0; m < 4; ++m)
        #pragma unroll
        for (int n = 0; n < 8; ++n)
            #pragma unroll
            for (int j = 0; j < 4; ++j) {
                int row = row0 + wr * 64 + m * 16 + l4 * 4 + j;
                int col = wc * 128 + n * 16 + l15;
                float h = sw * acc[m][n][j];
                float r = fmaxf(h, 0.f) / s1v;
                float qv = fminf(rintf(r), 15.f);
                A1[(size_t)row * 512 + col] = (signed char)qv;
                float fr = r - floorf(r);
                if (fabsf(fr - 0.5f) < FLAG_TOL) {
                    int p = atomicAdd(flagCnt, 1);
                    if (p < FLAG_CAP) flagList[p] = (unsigned)(row * 512 + col);
                }
            }
}

// ========== GEMM2: full-N i8 block (128 x 512), K=512 (unchanged, <=60us) ==========

__global__ __launch_bounds__(512, 2) void k_gemm2F(
    const signed char* __restrict__ A, const signed char* __restrict__ B,
    const float* __restrict__ wmax, const float* __restrict__ s1p, const float* __restrict__ s2p,
    signed char* __restrict__ A2, int* __restrict__ flagCnt, unsigned* __restrict__ flagList)
{
    constexpr int NT = 4;
    __shared__ __align__(16) signed char As[2][128 * 128];
    __shared__ __align__(16) signed char Bs[512 * 128];

    const int t = threadIdx.x;
    const int lane = t & 63, w = t >> 6;
    const int wr = w >> 2, wc = w & 3;
    const int l15 = lane & 15, l4 = lane >> 4;
    const int row0 = blockIdx.x * 128;

    i32x4 acc[4][8];
    #pragma unroll
    for (int m = 0; m < 4; ++m)
        #pragma unroll
        for (int n = 0; n < 8; ++n) acc[m][n] = (i32x4){0, 0, 0, 0};

    const int lr = lane >> 3;
    const int lcb = ((lane & 7) ^ lr) * 16;
    const signed char* Ab = A + (size_t)(row0 + lr) * 512 + lcb;
    const signed char* Bb = B + (size_t)lr * 512 + lcb;

    #pragma unroll
    for (int i = 0; i < 2; ++i) {
        int ch = w * 2 + i;
        gld16(Ab + (size_t)ch * 8 * 512, &As[0][ch * 1024]);
    }

    int cur = 0;
    for (int tt = 0; tt < NT; ++tt) {
        #pragma unroll
        for (int i = 0; i < 8; ++i) {
            int ch = w * 8 + i;
            gld16(Bb + (size_t)ch * 8 * 512 + tt * 128, &Bs[ch * 1024]);
        }
        SCHEDB();
        int tn = (tt + 1 < NT) ? tt + 1 : tt;
        #pragma unroll
        for (int i = 0; i < 2; ++i) {
            int ch = w * 2 + i;
            gld16(Ab + (size_t)ch * 8 * 512 + tn * 128, &As[cur ^ 1][ch * 1024]);
        }
        SCHEDB();
        asm volatile("s_waitcnt vmcnt(2)" ::: "memory");
        SBAR();

        #pragma unroll
        for (int kk = 0; kk < 2; ++kk) {
            int sl = kk * 4 + l4;
            int slw = (sl ^ (lane & 7)) * 16;
            i32x4 af[4], bf[8];
            #pragma unroll
            for (int m = 0; m < 4; ++m)
                af[m] = *reinterpret_cast<const i32x4*>(&As[cur][(wr * 64 + m * 16 + l15) * 128 + slw]);
            #pragma unroll
            for (int n = 0; n < 8; ++n)
                bf[n] = *reinterpret_cast<const i32x4*>(&Bs[(wc * 128 + n * 16 + l15) * 128 + slw]);
            #pragma unroll
            for (int m = 0; m < 4; ++m)
                #pragma unroll
                for (int n = 0; n < 8; ++n)
                    acc[m][n] = MFMAI8(af[m], bf[n], acc[m][n]);
        }

        SBAR();
        cur ^= 1;
    }

    double cs = (double)s1p[0] * (double)(wmax[0] / 7.0f + 1e-8f);
    double s2v = (double)s2p[0];
    #pragma unroll
    for (int m = 0; m < 4; ++m)
        #pragma unroll
        for (int n = 0; n < 8; ++n)
            #pragma unroll
            for (int j = 0; j < 4; ++j) {
                int row = row0 + wr * 64 + m * 16 + l4 * 4 + j;
                int col = wc * 128 + n * 16 + l15;
                double r = fmax((double)acc[m][n][j] * cs, 0.0) / s2v;
                double qv = fmin(rint(r), 15.0);
                A2[(size_t)row * 512 + col] = (signed char)qv;
                double fr = r - floor(r);
                if (fabs(fr - 0.5) < (double)FLAG_TOL && r < 16.0) {
                    int p = atomicAdd(flagCnt, 1);
                    if (p < FLAG_CAP) flagList[p] = (unsigned)(row * 512 + col);
                }
            }
}

// ---------------- fixups: BLAS-replicating sequential fp32 FMA ----------------

__global__ void k_fixup1(const float* __restrict__ X, const float* __restrict__ W1dq,
                         const float* __restrict__ s1p,
                         const int* __restrict__ flagCnt, const unsigned* __restrict__ flagList,
                         signed char* __restrict__ A1)
{
    int tid = blockIdx.x * blockDim.x + threadIdx.x;
    int nthr = gridDim.x * blockDim.x;
    int n = flagCnt[0];
    if (n > FLAG_CAP) n = FLAG_CAP;
    float s1 = s1p[0];
    for (int i = tid; i < n; i += nthr) {
        unsigned idx = flagList[i];
        int row = (int)(idx >> 9), col = (int)(idx & 511);
        const float* xr = X + (size_t)row * 784;
        const float* wr = W1dq + (size_t)col * 784;
        float acc = 0.f;
        for (int k = 0; k < 784; ++k)
            acc = fmaf(xr[k], wr[k], acc);       // k-ascending, single acc: BLAS order
        float tq = fmaxf(acc, 0.f) / s1;
        float code = fminf(rintf(tq), 15.f);
        A1[(size_t)row * 512 + col] = (signed char)code;
    }
}

__global__ void k_fixup2(const signed char* __restrict__ A1, const float* __restrict__ W2dq,
                         const float* __restrict__ s1p, const float* __restrict__ s2p,
                         const int* __restrict__ flagCnt, const unsigned* __restrict__ flagList,
                         signed char* __restrict__ A2)
{
    int tid = blockIdx.x * blockDim.x + threadIdx.x;
    int nthr = gridDim.x * blockDim.x;
    int n = flagCnt[0];
    if (n > FLAG_CAP) n = FLAG_CAP;
    float s1 = s1p[0], s2 = s2p[0];
    for (int i = tid; i < n; i += nthr) {
        unsigned idx = flagList[i];
        int row = (int)(idx >> 9), col = (int)(idx & 511);
        const signed char* ar = A1 + (size_t)row * 512;
        const float* wr = W2dq + (size_t)col * 512;
        float acc = 0.f;
        for (int k = 0; k < 512; ++k) {
            float adq = (float)ar[k] * s1;       // fp32 dequant, == ref
            acc = fmaf(adq, wr[k], acc);
        }
        float tq = fmaxf(acc, 0.f) / s2;
        float code = fminf(rintf(tq), 15.f);
        A2[(size_t)row * 512 + col] = (signed char)code;
    }
}

// ---------------- GEMM3: int8 [65536,512] @ [16,512]^T -> fp32 logits ----------------

__global__ __launch_bounds__(256) void k_gemm3i(
    const signed char* __restrict__ A2, const signed char* __restrict__ Q3,
    const float* __restrict__ wmax, const float* __restrict__ s2p,
    float* __restrict__ Out)
{
    __shared__ __align__(16) signed char As[256][80];
    __shared__ __align__(16) signed char Bs[16][80];

    const int t = threadIdx.x;
    const int row0 = blockIdx.x * 256;
    const int lane = t & 63, wv = t >> 6;

    i32x4 acc[4];
    #pragma unroll
    for (int m = 0; m < 4; ++m) acc[m] = (i32x4){0, 0, 0, 0};

    for (int k0 = 0; k0 < 512; k0 += 64) {
        #pragma unroll
        for (int i = 0; i < 4; ++i) {
            int f = t + 256 * i;
            int r = f >> 2, c = f & 3;
            *reinterpret_cast<uint4*>(&As[r][c * 16]) =
                *reinterpret_cast<const uint4*>(A2 + (size_t)(row0 + r) * 512 + k0 + c * 16);
        }
        if (t < 64) {
            int r = t >> 2, c = t & 3;
            *reinterpret_cast<uint4*>(&Bs[r][c * 16]) =
                *reinterpret_cast<const uint4*>(Q3 + (size_t)r * 512 + k0 + c * 16);
        }
        __syncthreads();

        i32x4 bf = *reinterpret_cast<const i32x4*>(&Bs[lane & 15][(lane >> 4) * 16]);
        #pragma unroll
        for (int m = 0; m < 4; ++m) {
            i32x4 af = *reinterpret_cast<const i32x4*>(&As[wv * 64 + m * 16 + (lane & 15)][(lane >> 4) * 16]);
            acc[m] = MFMAI8(af, bf, acc[m]);
        }
        __syncthreads();
    }

    double cs = (double)s2p[0] * (double)(wmax[0] / 7.0f + 1e-8f);
    #pragma unroll
    for (int m = 0; m < 4; ++m)
        #pragma unroll
        for (int j = 0; j < 4; ++j) {
            int row = row0 + wv * 64 + m * 16 + (lane >> 4) * 4 + j;
            int col = lane & 15;
            if (col < 10)
                Out[(size_t)row * 10 + col] = (float)((double)acc[m][j] * cs);
        }
}

// ---------------- launch ----------------

extern "C" void kernel_launch(void* const* d_in, const int* in_sizes, int n_in,
                              void* d_out, int out_size, void* d_ws, size_t ws_size,
                              hipStream_t stream)
{
    (void)in_sizes; (void)n_in; (void)out_size; (void)ws_size;

    const float* X  = (const float*)d_in[0];
    const float* W1 = (const float*)d_in[1];
    const float* W2 = (const float*)d_in[2];
    const float* W3 = (const float*)d_in[3];
    const float* s1 = (const float*)d_in[4];
    const float* s2 = (const float*)d_in[5];
    float* Out = (float*)d_out;

    char* ws = (char*)d_ws;
    float* maxes     = (float*)ws;
    int*   cnts      = (int*)(ws + 16);
    f16*   q1h       = (f16*)(ws + (size_t)(1u << 20));              // 852992 B
    float* w1dq      = (float*)(ws + (size_t)(2u << 20));            // 1605632 B
    float* w2dq      = (float*)(ws + (size_t)(4u << 20));            // 1048576 B
    signed char* q2i = (signed char*)(ws + (size_t)(6u << 20));      // 262144 B
    signed char* q3i = (signed char*)(ws + (size_t)(6u << 20) + 300000);  // 8192 B
    signed char* a1  = (signed char*)(ws + (size_t)(8u << 20));      // 32 MB
    signed char* a2  = (signed char*)(ws + (size_t)(40u << 20));     // 32 MB
    unsigned* fl1    = (unsigned*)(ws + (size_t)(72u << 20));        // 4 MB
    unsigned* fl2    = (unsigned*)(ws + (size_t)(76u << 20));        // 4 MB

    k_zero<<<1, 64, 0, stream>>>(maxes, cnts);
    k_absmax<<<256, 256, 0, stream>>>(W1, 512 * 784, maxes + 0);
    k_absmax<<<256, 256, 0, stream>>>(W2, 512 * 512, maxes + 1);
    k_absmax<<<8, 256, 0, stream>>>(W3, 10 * 512, maxes + 2);
    k_quantw1<<<(512 * 832 + 255) / 256, 256, 0, stream>>>(W1, maxes + 0, w1dq, q1h);
    k_quantw2<<<(512 * 512 + 255) / 256, 256, 0, stream>>>(W2, maxes + 1, q2i, w2dq, 512 * 512);
    k_quantw3<<<(16 * 512 + 255) / 256, 256, 0, stream>>>(W3, maxes + 2, q3i);

    k_gemm1G<<<512, 512, 0, stream>>>(X, q1h, maxes + 0, s1, a1, cnts + 0, fl1);
    k_fixup1<<<512, 256, 0, stream>>>(X, w1dq, s1, cnts + 0, fl1, a1);
    k_gemm2F<<<512, 512, 0, stream>>>(a1, q2i, maxes + 1, s1, s2, a2, cnts + 1, fl2);
    k_fixup2<<<512, 256, 0, stream>>>(a1, w2dq, s1, s2, cnts + 1, fl2, a2);
    k_gemm3i<<<256, 256, 0, stream>>>(a2, q3i, maxes + 2, s2, Out);
}

// Round 14
// 626.680 us; speedup vs baseline: 1.9989x; 1.9989x over previous
//
#include <hip/hip_runtime.h>
#include <hip/hip_fp16.h>

typedef _Float16 f16;
typedef _Float16 f16x4 __attribute__((ext_vector_type(4)));
typedef _Float16 f16x8 __attribute__((ext_vector_type(8)));
typedef float f32x4 __attribute__((ext_vector_type(4)));
typedef int i32x4 __attribute__((ext_vector_type(4)));

#define MFMA16(a, b, c) __builtin_amdgcn_mfma_f32_16x16x32_f16((a), (b), (c), 0, 0, 0)
#define MFMAI8(a, b, c) __builtin_amdgcn_mfma_i32_16x16x64_i8((a), (b), (c), 0, 0, 0)

#define FLAG_CAP (1024 * 1024)
#define FLAG_TOL 1e-3f

#define SBAR()   __builtin_amdgcn_s_barrier()
#define SCHEDB() __builtin_amdgcn_sched_barrier(0)

// async global->LDS, 16 B per lane. LDS dest is wave-uniform base (+lane*16);
// global src is per-lane (swizzle baked into source address).
__device__ __forceinline__ void gld16(const void* g, void* l) {
    __builtin_amdgcn_global_load_lds(
        (const __attribute__((address_space(1))) unsigned int*)g,
        (__attribute__((address_space(3))) unsigned int*)l,
        16, 0, 0);
}

// ---------------- scale computation ----------------

__global__ void k_zero(float* p, int* cnt) {
    if (threadIdx.x < 3) p[threadIdx.x] = 0.f;
    if (threadIdx.x == 3) { cnt[0] = 0; cnt[1] = 0; }
}

__global__ void k_absmax(const float* __restrict__ w, int n, float* __restrict__ out) {
    float m = 0.f;
    int stride = gridDim.x * blockDim.x;
    for (int i = blockIdx.x * blockDim.x + threadIdx.x; i < n; i += stride)
        m = fmaxf(m, fabsf(w[i]));
    #pragma unroll
    for (int o = 32; o > 0; o >>= 1) m = fmaxf(m, __shfl_down(m, o));
    __shared__ float sm[4];
    int lane = threadIdx.x & 63, wv = threadIdx.x >> 6;
    if (lane == 0) sm[wv] = m;
    __syncthreads();
    if (threadIdx.x == 0) {
        float mm = fmaxf(fmaxf(sm[0], sm[1]), fmaxf(sm[2], sm[3]));
        atomicMax((unsigned int*)out, __float_as_uint(mm));  // nonneg floats only
    }
}

// W1: fp32 dequant w1dq (fixup) + padded f16 panel q1h [512][832]
__global__ void k_quantw1(const float* __restrict__ w, const float* __restrict__ wmax,
                          float* __restrict__ wdq, f16* __restrict__ q1h) {
    int i = blockIdx.x * blockDim.x + threadIdx.x;
    if (i >= 512 * 832) return;
    int n = i / 832, k = i - n * 832;
    float v = 0.f;
    if (k < 784) {
        float s = wmax[0] / 7.0f + 1e-8f;
        v = rintf(w[n * 784 + k] / s);       // fp32 ops replicate numpy semantics
        v = fminf(fmaxf(v, -7.f), 7.f);
        wdq[n * 784 + k] = v * s;
    }
    q1h[(size_t)n * 832 + k] = (f16)v;
}

// W2: int8 codes + fp32 dequant (fixup)
__global__ void k_quantw2(const float* __restrict__ w, const float* __restrict__ wmax,
                          signed char* __restrict__ q, float* __restrict__ wdq, int n) {
    float s = wmax[0] / 7.0f + 1e-8f;
    int i = blockIdx.x * blockDim.x + threadIdx.x;
    if (i < n) {
        float v = rintf(w[i] / s);
        v = fminf(fmaxf(v, -7.f), 7.f);
        q[i] = (signed char)v;
        if (wdq) wdq[i] = v * s;
    }
}

// W3: int8, zero-padded to 16x512
__global__ void k_quantw3(const float* __restrict__ w, const float* __restrict__ wmax,
                          signed char* __restrict__ q) {
    float s = wmax[0] / 7.0f + 1e-8f;
    int i = blockIdx.x * blockDim.x + threadIdx.x;
    if (i < 16 * 512) {
        float v = 0.f;
        if (i < 10 * 512) {
            v = rintf(w[i] / s);
            v = fminf(fmaxf(v, -7.f), 7.f);
        }
        q[i] = (signed char)v;
    }
}

// ========== GEMM1: full-N block (128 x 512), K=832, BK=32, one-iteration load lead =====
// Loads for tile t+1 issued DURING tile t's body; the vmcnt(0) at the top of
// body t+1 references loads ~2400 MFMA-cycles old -> latency fully covered.
// launch_bounds(512,2): 1 block/CU, 256 regs/wave -> acc[4][8] fits in AGPRs,
// NO SPILL (round-12's (512,4) forced 128 regs -> accumulator spill, 2GB scratch).
// LDS rows 64B; element (r, 16B-slot s) at slot s^((r>>1)&3) -> 2-way banks (free).

__global__ __launch_bounds__(512, 2) void k_gemm1G(
    const float* __restrict__ X, const f16* __restrict__ B,
    const float* __restrict__ wmax, const float* __restrict__ s1p,
    signed char* __restrict__ A1, int* __restrict__ flagCnt, unsigned* __restrict__ flagList)
{
    constexpr int NT = 26;                       // 832/32 K-tiles
    __shared__ __align__(16) f16 Bt[2][512 * 32];    // 64 KB
    __shared__ __align__(16) f16 Ah[128 * 32];       // 8 KB
    __shared__ __align__(16) f16 Al[128 * 32];       // 8 KB

    const int t = threadIdx.x;
    const int lane = t & 63, w = t >> 6;
    const int wr = w >> 2, wc = w & 3;           // 2x4 wave grid; wave tile 64x128
    const int l15 = lane & 15, l4 = lane >> 4;
    const int row0 = blockIdx.x * 128;

    f32x4 acc[4][8];
    #pragma unroll
    for (int m = 0; m < 4; ++m)
        #pragma unroll
        for (int n = 0; n < 8; ++n) acc[m][n] = (f32x4){0.f, 0.f, 0.f, 0.f};

    // B staging map: chunk = 16 rows x 32 cols; lane -> (lr=lane>>2, slot=lane&3)
    // global src col-slot = slot ^ ((lr>>1)&3) so linear LDS holds swizzled layout
    const int blr = lane >> 2;
    const int bslot = (lane & 3) ^ ((lane >> 3) & 3);
    const f16* Bb = B + (size_t)blr * 832 + bslot * 8;

    // X (A) reg staging: thread covers 2 float4 of the 128x32 tile
    float4 av[2];
    auto LOADA = [&](int tn) {
        #pragma unroll
        for (int i = 0; i < 2; ++i) {
            int f = t + 512 * i;
            int r = f >> 3, s = f & 7;           // r:0..127, s: float4 slot 0..7
            int gk = tn * 32 + s * 4;
            av[i] = make_float4(0.f, 0.f, 0.f, 0.f);
            if (gk < 784)
                av[i] = *reinterpret_cast<const float4*>(X + (size_t)(row0 + r) * 784 + gk);
        }
    };
    // split av -> hi/lo, swizzled ds_write (8B halves of 16B slots)
    auto WRITEA = [&]() {
        #pragma unroll
        for (int i = 0; i < 2; ++i) {
            int f = t + 512 * i;
            int r = f >> 3, s = f & 7;
            float vv[4] = {av[i].x, av[i].y, av[i].z, av[i].w};
            f16x4 h0, h1;
            #pragma unroll
            for (int j = 0; j < 4; ++j) {
                f16 c0 = (f16)vv[j];                 // RNE
                h0[j] = c0;
                h1[j] = (f16)(vv[j] - (float)c0);    // exact residual
            }
            int slot = (s >> 1) ^ ((r >> 1) & 3);
            int ad = r * 32 + slot * 8 + (s & 1) * 4;   // f16 units
            *reinterpret_cast<f16x4*>(&Ah[ad]) = h0;
            *reinterpret_cast<f16x4*>(&Al[ad]) = h1;
        }
    };

    // prologue: issue B(0), X(0)
    {
        #pragma unroll
        for (int i = 0; i < 4; ++i) {
            int ch = w * 4 + i;                  // 32 chunks x 16 rows = 512
            gld16(Bb + (size_t)ch * 16 * 832, &Bt[0][ch * 512]);
        }
        LOADA(0);
    }

    int cur = 0;
    for (int tt = 0; tt < NT; ++tt) {
        asm volatile("s_waitcnt vmcnt(0)" ::: "memory");  // B(tt), X(tt) landed (issued 1 iter ago)
        SBAR();                                  // all waves: loads landed, done reading A(tt-1)
        WRITEA();                                // A(tt) -> LDS
        if (tt + 1 < NT) {                       // issue next tile's loads (land under compute)
            #pragma unroll
            for (int i = 0; i < 4; ++i) {
                int ch = w * 4 + i;
                gld16(Bb + (size_t)ch * 16 * 832 + (tt + 1) * 32, &Bt[cur ^ 1][ch * 512]);
            }
            LOADA(tt + 1);
        }
        SCHEDB();
        asm volatile("s_waitcnt lgkmcnt(0)" ::: "memory");  // my A ds_writes done
        SBAR();                                  // A(tt) visible to all; B(tt) ready

        // one K=32 step: 8 A-frag reads (hi+lo), 8 B-frag reads, 64 MFMA
        {
            f16x8 fh[4], fl_[4], bf[8];
            #pragma unroll
            for (int m = 0; m < 4; ++m) {
                int row = wr * 64 + m * 16 + l15;
                int ad = row * 32 + ((l4 ^ ((row >> 1) & 3)) * 8);
                fh[m]  = *reinterpret_cast<const f16x8*>(&Ah[ad]);
                fl_[m] = *reinterpret_cast<const f16x8*>(&Al[ad]);
            }
            #pragma unroll
            for (int n = 0; n < 8; ++n) {
                int row = wc * 128 + n * 16 + l15;
                int ad = row * 32 + ((l4 ^ ((row >> 1) & 3)) * 8);
                bf[n] = *reinterpret_cast<const f16x8*>(&Bt[cur][ad]);
            }
            #pragma unroll
            for (int m = 0; m < 4; ++m)
                #pragma unroll
                for (int n = 0; n < 8; ++n) {
                    acc[m][n] = MFMA16(fh[m],  bf[n], acc[m][n]);
                    acc[m][n] = MFMA16(fl_[m], bf[n], acc[m][n]);
                }
        }
        cur ^= 1;
    }

    float sw = wmax[0] / 7.0f + 1e-8f;
    float s1v = s1p[0];
    #pragma unroll
    for (int m = 0; m < 4; ++m)
        #pragma unroll
        for (int n = 0; n < 8; ++n)
            #pragma unroll
            for (int j = 0; j < 4; ++j) {
                int row = row0 + wr * 64 + m * 16 + l4 * 4 + j;
                int col = wc * 128 + n * 16 + l15;
                float h = sw * acc[m][n][j];
                float r = fmaxf(h, 0.f) / s1v;
                float qv = fminf(rintf(r), 15.f);
                A1[(size_t)row * 512 + col] = (signed char)qv;
                float fr = r - floorf(r);
                if (fabsf(fr - 0.5f) < FLAG_TOL) {
                    int p = atomicAdd(flagCnt, 1);
                    if (p < FLAG_CAP) flagList[p] = (unsigned)(row * 512 + col);
                }
            }
}

// ========== GEMM2: full-N i8 block (128 x 512), K=512 (unchanged) ==========

__global__ __launch_bounds__(512, 2) void k_gemm2F(
    const signed char* __restrict__ A, const signed char* __restrict__ B,
    const float* __restrict__ wmax, const float* __restrict__ s1p, const float* __restrict__ s2p,
    signed char* __restrict__ A2, int* __restrict__ flagCnt, unsigned* __restrict__ flagList)
{
    constexpr int NT = 4;
    __shared__ __align__(16) signed char As[2][128 * 128];
    __shared__ __align__(16) signed char Bs[512 * 128];

    const int t = threadIdx.x;
    const int lane = t & 63, w = t >> 6;
    const int wr = w >> 2, wc = w & 3;
    const int l15 = lane & 15, l4 = lane >> 4;
    const int row0 = blockIdx.x * 128;

    i32x4 acc[4][8];
    #pragma unroll
    for (int m = 0; m < 4; ++m)
        #pragma unroll
        for (int n = 0; n < 8; ++n) acc[m][n] = (i32x4){0, 0, 0, 0};

    const int lr = lane >> 3;
    const int lcb = ((lane & 7) ^ lr) * 16;
    const signed char* Ab = A + (size_t)(row0 + lr) * 512 + lcb;
    const signed char* Bb = B + (size_t)lr * 512 + lcb;

    #pragma unroll
    for (int i = 0; i < 2; ++i) {
        int ch = w * 2 + i;
        gld16(Ab + (size_t)ch * 8 * 512, &As[0][ch * 1024]);
    }

    int cur = 0;
    for (int tt = 0; tt < NT; ++tt) {
        #pragma unroll
        for (int i = 0; i < 8; ++i) {
            int ch = w * 8 + i;
            gld16(Bb + (size_t)ch * 8 * 512 + tt * 128, &Bs[ch * 1024]);
        }
        SCHEDB();
        int tn = (tt + 1 < NT) ? tt + 1 : tt;
        #pragma unroll
        for (int i = 0; i < 2; ++i) {
            int ch = w * 2 + i;
            gld16(Ab + (size_t)ch * 8 * 512 + tn * 128, &As[cur ^ 1][ch * 1024]);
        }
        SCHEDB();
        asm volatile("s_waitcnt vmcnt(2)" ::: "memory");
        SBAR();

        #pragma unroll
        for (int kk = 0; kk < 2; ++kk) {
            int sl = kk * 4 + l4;
            int slw = (sl ^ (lane & 7)) * 16;
            i32x4 af[4], bf[8];
            #pragma unroll
            for (int m = 0; m < 4; ++m)
                af[m] = *reinterpret_cast<const i32x4*>(&As[cur][(wr * 64 + m * 16 + l15) * 128 + slw]);
            #pragma unroll
            for (int n = 0; n < 8; ++n)
                bf[n] = *reinterpret_cast<const i32x4*>(&Bs[(wc * 128 + n * 16 + l15) * 128 + slw]);
            #pragma unroll
            for (int m = 0; m < 4; ++m)
                #pragma unroll
                for (int n = 0; n < 8; ++n)
                    acc[m][n] = MFMAI8(af[m], bf[n], acc[m][n]);
        }

        SBAR();
        cur ^= 1;
    }

    double cs = (double)s1p[0] * (double)(wmax[0] / 7.0f + 1e-8f);
    double s2v = (double)s2p[0];
    #pragma unroll
    for (int m = 0; m < 4; ++m)
        #pragma unroll
        for (int n = 0; n < 8; ++n)
            #pragma unroll
            for (int j = 0; j < 4; ++j) {
                int row = row0 + wr * 64 + m * 16 + l4 * 4 + j;
                int col = wc * 128 + n * 16 + l15;
                double r = fmax((double)acc[m][n][j] * cs, 0.0) / s2v;
                double qv = fmin(rint(r), 15.0);
                A2[(size_t)row * 512 + col] = (signed char)qv;
                double fr = r - floor(r);
                if (fabs(fr - 0.5) < (double)FLAG_TOL && r < 16.0) {
                    int p = atomicAdd(flagCnt, 1);
                    if (p < FLAG_CAP) flagList[p] = (unsigned)(row * 512 + col);
                }
            }
}

// ---------------- fixups: BLAS-replicating sequential fp32 FMA ----------------

__global__ void k_fixup1(const float* __restrict__ X, const float* __restrict__ W1dq,
                         const float* __restrict__ s1p,
                         const int* __restrict__ flagCnt, const unsigned* __restrict__ flagList,
                         signed char* __restrict__ A1)
{
    int tid = blockIdx.x * blockDim.x + threadIdx.x;
    int nthr = gridDim.x * blockDim.x;
    int n = flagCnt[0];
    if (n > FLAG_CAP) n = FLAG_CAP;
    float s1 = s1p[0];
    for (int i = tid; i < n; i += nthr) {
        unsigned idx = flagList[i];
        int row = (int)(idx >> 9), col = (int)(idx & 511);
        const float* xr = X + (size_t)row * 784;
        const float* wr = W1dq + (size_t)col * 784;
        float acc = 0.f;
        for (int k = 0; k < 784; ++k)
            acc = fmaf(xr[k], wr[k], acc);       // k-ascending, single acc: BLAS order
        float tq = fmaxf(acc, 0.f) / s1;
        float code = fminf(rintf(tq), 15.f);
        A1[(size_t)row * 512 + col] = (signed char)code;
    }
}

__global__ void k_fixup2(const signed char* __restrict__ A1, const float* __restrict__ W2dq,
                         const float* __restrict__ s1p, const float* __restrict__ s2p,
                         const int* __restrict__ flagCnt, const unsigned* __restrict__ flagList,
                         signed char* __restrict__ A2)
{
    int tid = blockIdx.x * blockDim.x + threadIdx.x;
    int nthr = gridDim.x * blockDim.x;
    int n = flagCnt[0];
    if (n > FLAG_CAP) n = FLAG_CAP;
    float s1 = s1p[0], s2 = s2p[0];
    for (int i = tid; i < n; i += nthr) {
        unsigned idx = flagList[i];
        int row = (int)(idx >> 9), col = (int)(idx & 511);
        const signed char* ar = A1 + (size_t)row * 512;
        const float* wr = W2dq + (size_t)col * 512;
        float acc = 0.f;
        for (int k = 0; k < 512; ++k) {
            float adq = (float)ar[k] * s1;       // fp32 dequant, == ref
            acc = fmaf(adq, wr[k], acc);
        }
        float tq = fmaxf(acc, 0.f) / s2;
        float code = fminf(rintf(tq), 15.f);
        A2[(size_t)row * 512 + col] = (signed char)code;
    }
}

// ---------------- GEMM3: int8 [65536,512] @ [16,512]^T -> fp32 logits ----------------

__global__ __launch_bounds__(256) void k_gemm3i(
    const signed char* __restrict__ A2, const signed char* __restrict__ Q3,
    const float* __restrict__ wmax, const float* __restrict__ s2p,
    float* __restrict__ Out)
{
    __shared__ __align__(16) signed char As[256][80];
    __shared__ __align__(16) signed char Bs[16][80];

    const int t = threadIdx.x;
    const int row0 = blockIdx.x * 256;
    const int lane = t & 63, wv = t >> 6;

    i32x4 acc[4];
    #pragma unroll
    for (int m = 0; m < 4; ++m) acc[m] = (i32x4){0, 0, 0, 0};

    for (int k0 = 0; k0 < 512; k0 += 64) {
        #pragma unroll
        for (int i = 0; i < 4; ++i) {
            int f = t + 256 * i;
            int r = f >> 2, c = f & 3;
            *reinterpret_cast<uint4*>(&As[r][c * 16]) =
                *reinterpret_cast<const uint4*>(A2 + (size_t)(row0 + r) * 512 + k0 + c * 16);
        }
        if (t < 64) {
            int r = t >> 2, c = t & 3;
            *reinterpret_cast<uint4*>(&Bs[r][c * 16]) =
                *reinterpret_cast<const uint4*>(Q3 + (size_t)r * 512 + k0 + c * 16);
        }
        __syncthreads();

        i32x4 bf = *reinterpret_cast<const i32x4*>(&Bs[lane & 15][(lane >> 4) * 16]);
        #pragma unroll
        for (int m = 0; m < 4; ++m) {
            i32x4 af = *reinterpret_cast<const i32x4*>(&As[wv * 64 + m * 16 + (lane & 15)][(lane >> 4) * 16]);
            acc[m] = MFMAI8(af, bf, acc[m]);
        }
        __syncthreads();
    }

    double cs = (double)s2p[0] * (double)(wmax[0] / 7.0f + 1e-8f);
    #pragma unroll
    for (int m = 0; m < 4; ++m)
        #pragma unroll
        for (int j = 0; j < 4; ++j) {
            int row = row0 + wv * 64 + m * 16 + (lane >> 4) * 4 + j;
            int col = lane & 15;
            if (col < 10)
                Out[(size_t)row * 10 + col] = (float)((double)acc[m][j] * cs);
        }
}

// ---------------- launch ----------------

extern "C" void kernel_launch(void* const* d_in, const int* in_sizes, int n_in,
                              void* d_out, int out_size, void* d_ws, size_t ws_size,
                              hipStream_t stream)
{
    (void)in_sizes; (void)n_in; (void)out_size; (void)ws_size;

    const float* X  = (const float*)d_in[0];
    const float* W1 = (const float*)d_in[1];
    const float* W2 = (const float*)d_in[2];
    const float* W3 = (const float*)d_in[3];
    const float* s1 = (const float*)d_in[4];
    const float* s2 = (const float*)d_in[5];
    float* Out = (float*)d_out;

    char* ws = (char*)d_ws;
    float* maxes     = (float*)ws;
    int*   cnts      = (int*)(ws + 16);
    f16*   q1h       = (f16*)(ws + (size_t)(1u << 20));              // 852992 B
    float* w1dq      = (float*)(ws + (size_t)(2u << 20));            // 1605632 B
    float* w2dq      = (float*)(ws + (size_t)(4u << 20));            // 1048576 B
    signed char* q2i = (signed char*)(ws + (size_t)(6u << 20));      // 262144 B
    signed char* q3i = (signed char*)(ws + (size_t)(6u << 20) + 300000);  // 8192 B
    signed char* a1  = (signed char*)(ws + (size_t)(8u << 20));      // 32 MB
    signed char* a2  = (signed char*)(ws + (size_t)(40u << 20));     // 32 MB
    unsigned* fl1    = (unsigned*)(ws + (size_t)(72u << 20));        // 4 MB
    unsigned* fl2    = (unsigned*)(ws + (size_t)(76u << 20));        // 4 MB

    k_zero<<<1, 64, 0, stream>>>(maxes, cnts);
    k_absmax<<<256, 256, 0, stream>>>(W1, 512 * 784, maxes + 0);
    k_absmax<<<256, 256, 0, stream>>>(W2, 512 * 512, maxes + 1);
    k_absmax<<<8, 256, 0, stream>>>(W3, 10 * 512, maxes + 2);
    k_quantw1<<<(512 * 832 + 255) / 256, 256, 0, stream>>>(W1, maxes + 0, w1dq, q1h);
    k_quantw2<<<(512 * 512 + 255) / 256, 256, 0, stream>>>(W2, maxes + 1, q2i, w2dq, 512 * 512);
    k_quantw3<<<(16 * 512 + 255) / 256, 256, 0, stream>>>(W3, maxes + 2, q3i);

    k_gemm1G<<<512, 512, 0, stream>>>(X, q1h, maxes + 0, s1, a1, cnts + 0, fl1);
    k_fixup1<<<512, 256, 0, stream>>>(X, w1dq, s1, cnts + 0, fl1, a1);
    k_gemm2F<<<512, 512, 0, stream>>>(a1, q2i, maxes + 1, s1, s2, a2, cnts + 1, fl2);
    k_fixup2<<<512, 256, 0, stream>>>(a1, w2dq, s1, s2, cnts + 1, fl2, a2);
    k_gemm3i<<<256, 256, 0, stream>>>(a2, q3i, maxes + 2, s2, Out);
}

// Round 15
// 617.163 us; speedup vs baseline: 2.0298x; 1.0154x over previous
//
#include <hip/hip_runtime.h>
#include <hip/hip_fp16.h>

typedef _Float16 f16;
typedef _Float16 f16x4 __attribute__((ext_vector_type(4)));
typedef _Float16 f16x8 __attribute__((ext_vector_type(8)));
typedef float f32x4 __attribute__((ext_vector_type(4)));
typedef int i32x4 __attribute__((ext_vector_type(4)));

#define MFMA16(a, b, c) __builtin_amdgcn_mfma_f32_16x16x32_f16((a), (b), (c), 0, 0, 0)
#define MFMAI8(a, b, c) __builtin_amdgcn_mfma_i32_16x16x64_i8((a), (b), (c), 0, 0, 0)

#define FLAG_CAP (1024 * 1024)
#define FLAG_TOL 1e-3f

#define SBAR()   __builtin_amdgcn_s_barrier()
#define SCHEDB() __builtin_amdgcn_sched_barrier(0)

// async global->LDS, 16 B per lane (still used by gemm2F).
__device__ __forceinline__ void gld16(const void* g, void* l) {
    __builtin_amdgcn_global_load_lds(
        (const __attribute__((address_space(1))) unsigned int*)g,
        (__attribute__((address_space(3))) unsigned int*)l,
        16, 0, 0);
}

// ---------------- scale computation ----------------

__global__ void k_zero(float* p, int* cnt) {
    if (threadIdx.x < 3) p[threadIdx.x] = 0.f;
    if (threadIdx.x == 3) { cnt[0] = 0; cnt[1] = 0; }
}

__global__ void k_absmax(const float* __restrict__ w, int n, float* __restrict__ out) {
    float m = 0.f;
    int stride = gridDim.x * blockDim.x;
    for (int i = blockIdx.x * blockDim.x + threadIdx.x; i < n; i += stride)
        m = fmaxf(m, fabsf(w[i]));
    #pragma unroll
    for (int o = 32; o > 0; o >>= 1) m = fmaxf(m, __shfl_down(m, o));
    __shared__ float sm[4];
    int lane = threadIdx.x & 63, wv = threadIdx.x >> 6;
    if (lane == 0) sm[wv] = m;
    __syncthreads();
    if (threadIdx.x == 0) {
        float mm = fmaxf(fmaxf(sm[0], sm[1]), fmaxf(sm[2], sm[3]));
        atomicMax((unsigned int*)out, __float_as_uint(mm));  // nonneg floats only
    }
}

// W1: fp32 dequant w1dq (fixup) + padded f16 panel q1h [512][832]
__global__ void k_quantw1(const float* __restrict__ w, const float* __restrict__ wmax,
                          float* __restrict__ wdq, f16* __restrict__ q1h) {
    int i = blockIdx.x * blockDim.x + threadIdx.x;
    if (i >= 512 * 832) return;
    int n = i / 832, k = i - n * 832;
    float v = 0.f;
    if (k < 784) {
        float s = wmax[0] / 7.0f + 1e-8f;
        v = rintf(w[n * 784 + k] / s);       // fp32 ops replicate numpy semantics
        v = fminf(fmaxf(v, -7.f), 7.f);
        wdq[n * 784 + k] = v * s;
    }
    q1h[(size_t)n * 832 + k] = (f16)v;
}

// W2: int8 codes + fp32 dequant (fixup)
__global__ void k_quantw2(const float* __restrict__ w, const float* __restrict__ wmax,
                          signed char* __restrict__ q, float* __restrict__ wdq, int n) {
    float s = wmax[0] / 7.0f + 1e-8f;
    int i = blockIdx.x * blockDim.x + threadIdx.x;
    if (i < n) {
        float v = rintf(w[i] / s);
        v = fminf(fmaxf(v, -7.f), 7.f);
        q[i] = (signed char)v;
        if (wdq) wdq[i] = v * s;
    }
}

// W3: int8, zero-padded to 16x512
__global__ void k_quantw3(const float* __restrict__ w, const float* __restrict__ wmax,
                          signed char* __restrict__ q) {
    float s = wmax[0] / 7.0f + 1e-8f;
    int i = blockIdx.x * blockDim.x + threadIdx.x;
    if (i < 16 * 512) {
        float v = 0.f;
        if (i < 10 * 512) {
            v = rintf(w[i] / s);
            v = fminf(fmaxf(v, -7.f), 7.f);
        }
        q[i] = (signed char)v;
    }
}

// ========== GEMM1 "W": wave-autonomous, ZERO LDS, ZERO barriers ==========
// Each wave owns a 32x128 output tile: acc[2][8] in AGPRs. X fragments load
// straight to registers (fp32 -> in-reg hi/lo f16 split); B fragments load
// straight from q1h (852 KB, L2-resident on every XCD). Software-pipelined
// unroll-2 with two NAMED register sets (no dynamic indexing -> no scratch).
// No rendezvous points: each wave free-runs; compiler scoreboard emits exact
// counted s_waitcnt per use. K-tiles >= 784 are all-zero and skipped (NT=25).

__global__ __launch_bounds__(512) void k_gemm1W(
    const float* __restrict__ X, const f16* __restrict__ B,
    const float* __restrict__ wmax, const float* __restrict__ s1p,
    signed char* __restrict__ A1, int* __restrict__ flagCnt, unsigned* __restrict__ flagList)
{
    constexpr int NT = 25;                       // ceil(784/32); tiles >=784 are zero
    const int t = threadIdx.x;
    const int lane = t & 63, w = t >> 6;         // 8 waves
    const int l15 = lane & 15, l4 = lane >> 4;
    const int row0 = blockIdx.x * 64 + (w >> 2) * 32;   // wave M-base (32 rows)
    const int col0 = (w & 3) * 128;                      // wave N-base (128 cols)

    f32x4 acc[2][8];
    #pragma unroll
    for (int m = 0; m < 2; ++m)
        #pragma unroll
        for (int n = 0; n < 8; ++n) acc[m][n] = (f32x4){0.f, 0.f, 0.f, 0.f};

    // per-lane base pointers (A-frag: row = l15 within 16-row frag, k-slice = l4*8)
    const float* Xb = X + (size_t)(row0 + l15) * 784 + l4 * 8;
    const f16*   Bb = B + (size_t)(col0 + l15) * 832 + l4 * 8;

    struct Set { float4 x[2][2]; f16x8 b[8]; };
    Set s0, s1;

    auto LOAD = [&](Set& s, int k0) {
        #pragma unroll
        for (int m = 0; m < 2; ++m)
            #pragma unroll
            for (int i = 0; i < 2; ++i) {
                int gk = k0 + l4 * 8 + i * 4;            // multiple of 4
                s.x[m][i] = make_float4(0.f, 0.f, 0.f, 0.f);
                if (gk < 784)                            // gk<784 <=> gk+3<=783
                    s.x[m][i] = *reinterpret_cast<const float4*>(
                        Xb + (size_t)m * 16 * 784 + k0 + i * 4);
            }
        #pragma unroll
        for (int n = 0; n < 8; ++n)                      // B padded to 832: no pred
            s.b[n] = *reinterpret_cast<const f16x8*>(Bb + (size_t)n * 16 * 832 + k0);
    };

    auto COMP = [&](Set& s) {
        f16x8 ah[2], al[2];
        #pragma unroll
        for (int m = 0; m < 2; ++m)
            #pragma unroll
            for (int i = 0; i < 2; ++i) {
                float vv[4] = {s.x[m][i].x, s.x[m][i].y, s.x[m][i].z, s.x[m][i].w};
                #pragma unroll
                for (int j = 0; j < 4; ++j) {
                    f16 c0 = (f16)vv[j];                 // RNE
                    ah[m][i * 4 + j] = c0;
                    al[m][i * 4 + j] = (f16)(vv[j] - (float)c0);  // exact residual
                }
            }
        #pragma unroll
        for (int m = 0; m < 2; ++m)
            #pragma unroll
            for (int n = 0; n < 8; ++n) {                // same order as rounds 9-14
                acc[m][n] = MFMA16(ah[m], s.b[n], acc[m][n]);
                acc[m][n] = MFMA16(al[m], s.b[n], acc[m][n]);
            }
    };

    LOAD(s0, 0);
    int tt = 0;
    for (; tt + 2 < NT; tt += 2) {
        LOAD(s1, (tt + 1) * 32);     // issue next while s0 computes
        COMP(s0);
        LOAD(s0, (tt + 2) * 32);
        COMP(s1);
    }
    COMP(s0);                        // tile 24 (predicated cols >=784 are zero)

    float sw = wmax[0] / 7.0f + 1e-8f;
    float s1v = s1p[0];
    #pragma unroll
    for (int m = 0; m < 2; ++m)
        #pragma unroll
        for (int n = 0; n < 8; ++n)
            #pragma unroll
            for (int j = 0; j < 4; ++j) {
                int row = row0 + m * 16 + l4 * 4 + j;
                int col = col0 + n * 16 + l15;
                float h = sw * acc[m][n][j];
                float r = fmaxf(h, 0.f) / s1v;
                float qv = fminf(rintf(r), 15.f);
                A1[(size_t)row * 512 + col] = (signed char)qv;
                float fr = r - floorf(r);
                if (fabsf(fr - 0.5f) < FLAG_TOL) {
                    int p = atomicAdd(flagCnt, 1);
                    if (p < FLAG_CAP) flagList[p] = (unsigned)(row * 512 + col);
                }
            }
}

// ========== GEMM2: full-N i8 block (128 x 512), K=512 (unchanged) ==========

__global__ __launch_bounds__(512, 2) void k_gemm2F(
    const signed char* __restrict__ A, const signed char* __restrict__ B,
    const float* __restrict__ wmax, const float* __restrict__ s1p, const float* __restrict__ s2p,
    signed char* __restrict__ A2, int* __restrict__ flagCnt, unsigned* __restrict__ flagList)
{
    constexpr int NT = 4;
    __shared__ __align__(16) signed char As[2][128 * 128];
    __shared__ __align__(16) signed char Bs[512 * 128];

    const int t = threadIdx.x;
    const int lane = t & 63, w = t >> 6;
    const int wr = w >> 2, wc = w & 3;
    const int l15 = lane & 15, l4 = lane >> 4;
    const int row0 = blockIdx.x * 128;

    i32x4 acc[4][8];
    #pragma unroll
    for (int m = 0; m < 4; ++m)
        #pragma unroll
        for (int n = 0; n < 8; ++n) acc[m][n] = (i32x4){0, 0, 0, 0};

    const int lr = lane >> 3;
    const int lcb = ((lane & 7) ^ lr) * 16;
    const signed char* Ab = A + (size_t)(row0 + lr) * 512 + lcb;
    const signed char* Bb = B + (size_t)lr * 512 + lcb;

    #pragma unroll
    for (int i = 0; i < 2; ++i) {
        int ch = w * 2 + i;
        gld16(Ab + (size_t)ch * 8 * 512, &As[0][ch * 1024]);
    }

    int cur = 0;
    for (int tt = 0; tt < NT; ++tt) {
        #pragma unroll
        for (int i = 0; i < 8; ++i) {
            int ch = w * 8 + i;
            gld16(Bb + (size_t)ch * 8 * 512 + tt * 128, &Bs[ch * 1024]);
        }
        SCHEDB();
        int tn = (tt + 1 < NT) ? tt + 1 : tt;
        #pragma unroll
        for (int i = 0; i < 2; ++i) {
            int ch = w * 2 + i;
            gld16(Ab + (size_t)ch * 8 * 512 + tn * 128, &As[cur ^ 1][ch * 1024]);
        }
        SCHEDB();
        asm volatile("s_waitcnt vmcnt(2)" ::: "memory");
        SBAR();

        #pragma unroll
        for (int kk = 0; kk < 2; ++kk) {
            int sl = kk * 4 + l4;
            int slw = (sl ^ (lane & 7)) * 16;
            i32x4 af[4], bf[8];
            #pragma unroll
            for (int m = 0; m < 4; ++m)
                af[m] = *reinterpret_cast<const i32x4*>(&As[cur][(wr * 64 + m * 16 + l15) * 128 + slw]);
            #pragma unroll
            for (int n = 0; n < 8; ++n)
                bf[n] = *reinterpret_cast<const i32x4*>(&Bs[(wc * 128 + n * 16 + l15) * 128 + slw]);
            #pragma unroll
            for (int m = 0; m < 4; ++m)
                #pragma unroll
                for (int n = 0; n < 8; ++n)
                    acc[m][n] = MFMAI8(af[m], bf[n], acc[m][n]);
        }

        SBAR();
        cur ^= 1;
    }

    double cs = (double)s1p[0] * (double)(wmax[0] / 7.0f + 1e-8f);
    double s2v = (double)s2p[0];
    #pragma unroll
    for (int m = 0; m < 4; ++m)
        #pragma unroll
        for (int n = 0; n < 8; ++n)
            #pragma unroll
            for (int j = 0; j < 4; ++j) {
                int row = row0 + wr * 64 + m * 16 + l4 * 4 + j;
                int col = wc * 128 + n * 16 + l15;
                double r = fmax((double)acc[m][n][j] * cs, 0.0) / s2v;
                double qv = fmin(rint(r), 15.0);
                A2[(size_t)row * 512 + col] = (signed char)qv;
                double fr = r - floor(r);
                if (fabs(fr - 0.5) < (double)FLAG_TOL && r < 16.0) {
                    int p = atomicAdd(flagCnt, 1);
                    if (p < FLAG_CAP) flagList[p] = (unsigned)(row * 512 + col);
                }
            }
}

// ---------------- fixups: BLAS-replicating sequential fp32 FMA ----------------

__global__ void k_fixup1(const float* __restrict__ X, const float* __restrict__ W1dq,
                         const float* __restrict__ s1p,
                         const int* __restrict__ flagCnt, const unsigned* __restrict__ flagList,
                         signed char* __restrict__ A1)
{
    int tid = blockIdx.x * blockDim.x + threadIdx.x;
    int nthr = gridDim.x * blockDim.x;
    int n = flagCnt[0];
    if (n > FLAG_CAP) n = FLAG_CAP;
    float s1 = s1p[0];
    for (int i = tid; i < n; i += nthr) {
        unsigned idx = flagList[i];
        int row = (int)(idx >> 9), col = (int)(idx & 511);
        const float* xr = X + (size_t)row * 784;
        const float* wr = W1dq + (size_t)col * 784;
        float acc = 0.f;
        for (int k = 0; k < 784; ++k)
            acc = fmaf(xr[k], wr[k], acc);       // k-ascending, single acc: BLAS order
        float tq = fmaxf(acc, 0.f) / s1;
        float code = fminf(rintf(tq), 15.f);
        A1[(size_t)row * 512 + col] = (signed char)code;
    }
}

__global__ void k_fixup2(const signed char* __restrict__ A1, const float* __restrict__ W2dq,
                         const float* __restrict__ s1p, const float* __restrict__ s2p,
                         const int* __restrict__ flagCnt, const unsigned* __restrict__ flagList,
                         signed char* __restrict__ A2)
{
    int tid = blockIdx.x * blockDim.x + threadIdx.x;
    int nthr = gridDim.x * blockDim.x;
    int n = flagCnt[0];
    if (n > FLAG_CAP) n = FLAG_CAP;
    float s1 = s1p[0], s2 = s2p[0];
    for (int i = tid; i < n; i += nthr) {
        unsigned idx = flagList[i];
        int row = (int)(idx >> 9), col = (int)(idx & 511);
        const signed char* ar = A1 + (size_t)row * 512;
        const float* wr = W2dq + (size_t)col * 512;
        float acc = 0.f;
        for (int k = 0; k < 512; ++k) {
            float adq = (float)ar[k] * s1;       // fp32 dequant, == ref
            acc = fmaf(adq, wr[k], acc);
        }
        float tq = fmaxf(acc, 0.f) / s2;
        float code = fminf(rintf(tq), 15.f);
        A2[(size_t)row * 512 + col] = (signed char)code;
    }
}

// ---------------- GEMM3: int8 [65536,512] @ [16,512]^T -> fp32 logits ----------------

__global__ __launch_bounds__(256) void k_gemm3i(
    const signed char* __restrict__ A2, const signed char* __restrict__ Q3,
    const float* __restrict__ wmax, const float* __restrict__ s2p,
    float* __restrict__ Out)
{
    __shared__ __align__(16) signed char As[256][80];
    __shared__ __align__(16) signed char Bs[16][80];

    const int t = threadIdx.x;
    const int row0 = blockIdx.x * 256;
    const int lane = t & 63, wv = t >> 6;

    i32x4 acc[4];
    #pragma unroll
    for (int m = 0; m < 4; ++m) acc[m] = (i32x4){0, 0, 0, 0};

    for (int k0 = 0; k0 < 512; k0 += 64) {
        #pragma unroll
        for (int i = 0; i < 4; ++i) {
            int f = t + 256 * i;
            int r = f >> 2, c = f & 3;
            *reinterpret_cast<uint4*>(&As[r][c * 16]) =
                *reinterpret_cast<const uint4*>(A2 + (size_t)(row0 + r) * 512 + k0 + c * 16);
        }
        if (t < 64) {
            int r = t >> 2, c = t & 3;
            *reinterpret_cast<uint4*>(&Bs[r][c * 16]) =
                *reinterpret_cast<const uint4*>(Q3 + (size_t)r * 512 + k0 + c * 16);
        }
        __syncthreads();

        i32x4 bf = *reinterpret_cast<const i32x4*>(&Bs[lane & 15][(lane >> 4) * 16]);
        #pragma unroll
        for (int m = 0; m < 4; ++m) {
            i32x4 af = *reinterpret_cast<const i32x4*>(&As[wv * 64 + m * 16 + (lane & 15)][(lane >> 4) * 16]);
            acc[m] = MFMAI8(af, bf, acc[m]);
        }
        __syncthreads();
    }

    double cs = (double)s2p[0] * (double)(wmax[0] / 7.0f + 1e-8f);
    #pragma unroll
    for (int m = 0; m < 4; ++m)
        #pragma unroll
        for (int j = 0; j < 4; ++j) {
            int row = row0 + wv * 64 + m * 16 + (lane >> 4) * 4 + j;
            int col = lane & 15;
            if (col < 10)
                Out[(size_t)row * 10 + col] = (float)((double)acc[m][j] * cs);
        }
}

// ---------------- launch ----------------

extern "C" void kernel_launch(void* const* d_in, const int* in_sizes, int n_in,
                              void* d_out, int out_size, void* d_ws, size_t ws_size,
                              hipStream_t stream)
{
    (void)in_sizes; (void)n_in; (void)out_size; (void)ws_size;

    const float* X  = (const float*)d_in[0];
    const float* W1 = (const float*)d_in[1];
    const float* W2 = (const float*)d_in[2];
    const float* W3 = (const float*)d_in[3];
    const float* s1 = (const float*)d_in[4];
    const float* s2 = (const float*)d_in[5];
    float* Out = (float*)d_out;

    char* ws = (char*)d_ws;
    float* maxes     = (float*)ws;
    int*   cnts      = (int*)(ws + 16);
    f16*   q1h       = (f16*)(ws + (size_t)(1u << 20));              // 852992 B
    float* w1dq      = (float*)(ws + (size_t)(2u << 20));            // 1605632 B
    float* w2dq      = (float*)(ws + (size_t)(4u << 20));            // 1048576 B
    signed char* q2i = (signed char*)(ws + (size_t)(6u << 20));      // 262144 B
    signed char* q3i = (signed char*)(ws + (size_t)(6u << 20) + 300000);  // 8192 B
    signed char* a1  = (signed char*)(ws + (size_t)(8u << 20));      // 32 MB
    signed char* a2  = (signed char*)(ws + (size_t)(40u << 20));     // 32 MB
    unsigned* fl1    = (unsigned*)(ws + (size_t)(72u << 20));        // 4 MB
    unsigned* fl2    = (unsigned*)(ws + (size_t)(76u << 20));        // 4 MB

    k_zero<<<1, 64, 0, stream>>>(maxes, cnts);
    k_absmax<<<256, 256, 0, stream>>>(W1, 512 * 784, maxes + 0);
    k_absmax<<<256, 256, 0, stream>>>(W2, 512 * 512, maxes + 1);
    k_absmax<<<8, 256, 0, stream>>>(W3, 10 * 512, maxes + 2);
    k_quantw1<<<(512 * 832 + 255) / 256, 256, 0, stream>>>(W1, maxes + 0, w1dq, q1h);
    k_quantw2<<<(512 * 512 + 255) / 256, 256, 0, stream>>>(W2, maxes + 1, q2i, w2dq, 512 * 512);
    k_quantw3<<<(16 * 512 + 255) / 256, 256, 0, stream>>>(W3, maxes + 2, q3i);

    k_gemm1W<<<1024, 512, 0, stream>>>(X, q1h, maxes + 0, s1, a1, cnts + 0, fl1);
    k_fixup1<<<512, 256, 0, stream>>>(X, w1dq, s1, cnts + 0, fl1, a1);
    k_gemm2F<<<512, 512, 0, stream>>>(a1, q2i, maxes + 1, s1, s2, a2, cnts + 1, fl2);
    k_fixup2<<<512, 256, 0, stream>>>(a1, w2dq, s1, s2, cnts + 1, fl2, a2);
    k_gemm3i<<<256, 256, 0, stream>>>(a2, q3i, maxes + 2, s2, Out);
}

// Round 16
// 585.897 us; speedup vs baseline: 2.1381x; 1.0534x over previous
//
#include <hip/hip_runtime.h>
#include <hip/hip_fp16.h>

typedef _Float16 f16;
typedef _Float16 f16x4 __attribute__((ext_vector_type(4)));
typedef _Float16 f16x8 __attribute__((ext_vector_type(8)));
typedef float f32x4 __attribute__((ext_vector_type(4)));
typedef int i32x4 __attribute__((ext_vector_type(4)));

#define MFMA16(a, b, c) __builtin_amdgcn_mfma_f32_16x16x32_f16((a), (b), (c), 0, 0, 0)
#define MFMAI8(a, b, c) __builtin_amdgcn_mfma_i32_16x16x64_i8((a), (b), (c), 0, 0, 0)

#define FLAG_CAP (1024 * 1024)
#define FLAG_TOL 1e-3f

#define SBAR()   __builtin_amdgcn_s_barrier()
#define SCHEDB() __builtin_amdgcn_sched_barrier(0)

// async global->LDS, 16 B per lane (used by gemm2F).
__device__ __forceinline__ void gld16(const void* g, void* l) {
    __builtin_amdgcn_global_load_lds(
        (const __attribute__((address_space(1))) unsigned int*)g,
        (__attribute__((address_space(3))) unsigned int*)l,
        16, 0, 0);
}

// ---------------- scale computation ----------------

__global__ void k_zero(float* p, int* cnt) {
    if (threadIdx.x < 3) p[threadIdx.x] = 0.f;
    if (threadIdx.x == 3) { cnt[0] = 0; cnt[1] = 0; }
}

__global__ void k_absmax(const float* __restrict__ w, int n, float* __restrict__ out) {
    float m = 0.f;
    int stride = gridDim.x * blockDim.x;
    for (int i = blockIdx.x * blockDim.x + threadIdx.x; i < n; i += stride)
        m = fmaxf(m, fabsf(w[i]));
    #pragma unroll
    for (int o = 32; o > 0; o >>= 1) m = fmaxf(m, __shfl_down(m, o));
    __shared__ float sm[4];
    int lane = threadIdx.x & 63, wv = threadIdx.x >> 6;
    if (lane == 0) sm[wv] = m;
    __syncthreads();
    if (threadIdx.x == 0) {
        float mm = fmaxf(fmaxf(sm[0], sm[1]), fmaxf(sm[2], sm[3]));
        atomicMax((unsigned int*)out, __float_as_uint(mm));  // nonneg floats only
    }
}

// W1: fp32 dequant w1dq (fixup) + padded f16 panel q1h [512][832]
__global__ void k_quantw1(const float* __restrict__ w, const float* __restrict__ wmax,
                          float* __restrict__ wdq, f16* __restrict__ q1h) {
    int i = blockIdx.x * blockDim.x + threadIdx.x;
    if (i >= 512 * 832) return;
    int n = i / 832, k = i - n * 832;
    float v = 0.f;
    if (k < 784) {
        float s = wmax[0] / 7.0f + 1e-8f;
        v = rintf(w[n * 784 + k] / s);       // fp32 ops replicate numpy semantics
        v = fminf(fmaxf(v, -7.f), 7.f);
        wdq[n * 784 + k] = v * s;
    }
    q1h[(size_t)n * 832 + k] = (f16)v;
}

// W2: int8 codes + fp32 dequant (fixup)
__global__ void k_quantw2(const float* __restrict__ w, const float* __restrict__ wmax,
                          signed char* __restrict__ q, float* __restrict__ wdq, int n) {
    float s = wmax[0] / 7.0f + 1e-8f;
    int i = blockIdx.x * blockDim.x + threadIdx.x;
    if (i < n) {
        float v = rintf(w[i] / s);
        v = fminf(fmaxf(v, -7.f), 7.f);
        q[i] = (signed char)v;
        if (wdq) wdq[i] = v * s;
    }
}

// W3: int8, zero-padded to 16x512
__global__ void k_quantw3(const float* __restrict__ w, const float* __restrict__ wmax,
                          signed char* __restrict__ q) {
    float s = wmax[0] / 7.0f + 1e-8f;
    int i = blockIdx.x * blockDim.x + threadIdx.x;
    if (i < 16 * 512) {
        float v = 0.f;
        if (i < 10 * 512) {
            v = rintf(w[i] / s);
            v = fminf(fmaxf(v, -7.f), 7.f);
        }
        q[i] = (signed char)v;
    }
}

// ========== GEMM1 "W2": wave-autonomous, zero LDS/barriers, HIGH OCCUPANCY ==========
// Wave tile 32x64: acc[2][4] = 32 AGPR; ~112-118 regs/wave -> 4 waves/SIMD
// (16 waves/CU, 50% occupancy — 2x round 15). 256-thr blocks (4 waves = 64x128
// block tile), 4096 blocks, chunked XCD swizzle (4 col-blocks of a row-panel
// -> same XCD for X L2 reuse). Reg-direct loads, unroll-2 named sets.

__global__ __launch_bounds__(256, 4) void k_gemm1W2(
    const float* __restrict__ X, const f16* __restrict__ B,
    const float* __restrict__ wmax, const float* __restrict__ s1p,
    signed char* __restrict__ A1, int* __restrict__ flagCnt, unsigned* __restrict__ flagList)
{
    constexpr int NT = 25;                       // ceil(784/32); tiles >=784 are zero
    const int t = threadIdx.x;
    const int lane = t & 63, w = t >> 6;         // 4 waves
    const int l15 = lane & 15, l4 = lane >> 4;

    // chunked XCD swizzle: consecutive lg (same XCD) cover the 4 col-groups
    // of one 64-row panel -> X panel served once per XCD L2
    const int bid = blockIdx.x;                  // 4096 blocks
    const int lg = (bid & 7) * 512 + (bid >> 3);
    const int rowg = lg >> 2, colg = lg & 3;
    const int row0 = rowg * 64 + (w >> 1) * 32;  // wave M-base (32 rows)
    const int col0 = colg * 128 + (w & 1) * 64;  // wave N-base (64 cols)

    f32x4 acc[2][4];
    #pragma unroll
    for (int m = 0; m < 2; ++m)
        #pragma unroll
        for (int n = 0; n < 4; ++n) acc[m][n] = (f32x4){0.f, 0.f, 0.f, 0.f};

    const float* Xb = X + (size_t)(row0 + l15) * 784 + l4 * 8;
    const f16*   Bb = B + (size_t)(col0 + l15) * 832 + l4 * 8;

    struct Set { float4 x[2][2]; f16x8 b[4]; };
    Set s0, s1;

    auto LOAD = [&](Set& s, int k0) {
        #pragma unroll
        for (int m = 0; m < 2; ++m)
            #pragma unroll
            for (int i = 0; i < 2; ++i) {
                int gk = k0 + l4 * 8 + i * 4;            // multiple of 4
                s.x[m][i] = make_float4(0.f, 0.f, 0.f, 0.f);
                if (gk < 784)
                    s.x[m][i] = *reinterpret_cast<const float4*>(
                        Xb + (size_t)m * 16 * 784 + k0 + i * 4);
            }
        #pragma unroll
        for (int n = 0; n < 4; ++n)                      // B padded to 832: no pred
            s.b[n] = *reinterpret_cast<const f16x8*>(Bb + (size_t)n * 16 * 832 + k0);
    };

    auto COMP = [&](Set& s) {
        f16x8 ah[2], al[2];
        #pragma unroll
        for (int m = 0; m < 2; ++m)
            #pragma unroll
            for (int i = 0; i < 2; ++i) {
                float vv[4] = {s.x[m][i].x, s.x[m][i].y, s.x[m][i].z, s.x[m][i].w};
                #pragma unroll
                for (int j = 0; j < 4; ++j) {
                    f16 c0 = (f16)vv[j];                 // RNE
                    ah[m][i * 4 + j] = c0;
                    al[m][i * 4 + j] = (f16)(vv[j] - (float)c0);  // exact residual
                }
            }
        #pragma unroll
        for (int m = 0; m < 2; ++m)
            #pragma unroll
            for (int n = 0; n < 4; ++n) {                // same per-output order as r9-15
                acc[m][n] = MFMA16(ah[m], s.b[n], acc[m][n]);
                acc[m][n] = MFMA16(al[m], s.b[n], acc[m][n]);
            }
    };

    LOAD(s0, 0);
    int tt = 0;
    for (; tt + 2 < NT; tt += 2) {
        LOAD(s1, (tt + 1) * 32);     // issue next while s0 computes
        COMP(s0);
        LOAD(s0, (tt + 2) * 32);
        COMP(s1);
    }
    COMP(s0);                        // tile 24 (predicated cols >=784 are zero)

    float sw = wmax[0] / 7.0f + 1e-8f;
    float s1v = s1p[0];
    #pragma unroll
    for (int m = 0; m < 2; ++m)
        #pragma unroll
        for (int n = 0; n < 4; ++n)
            #pragma unroll
            for (int j = 0; j < 4; ++j) {
                int row = row0 + m * 16 + l4 * 4 + j;
                int col = col0 + n * 16 + l15;
                float h = sw * acc[m][n][j];
                float r = fmaxf(h, 0.f) / s1v;
                float qv = fminf(rintf(r), 15.f);
                A1[(size_t)row * 512 + col] = (signed char)qv;
                float fr = r - floorf(r);
                if (fabsf(fr - 0.5f) < FLAG_TOL) {
                    int p = atomicAdd(flagCnt, 1);
                    if (p < FLAG_CAP) flagList[p] = (unsigned)(row * 512 + col);
                }
            }
}

// ========== GEMM2: full-N i8 block (128 x 512), K=512 (unchanged) ==========

__global__ __launch_bounds__(512, 2) void k_gemm2F(
    const signed char* __restrict__ A, const signed char* __restrict__ B,
    const float* __restrict__ wmax, const float* __restrict__ s1p, const float* __restrict__ s2p,
    signed char* __restrict__ A2, int* __restrict__ flagCnt, unsigned* __restrict__ flagList)
{
    constexpr int NT = 4;
    __shared__ __align__(16) signed char As[2][128 * 128];
    __shared__ __align__(16) signed char Bs[512 * 128];

    const int t = threadIdx.x;
    const int lane = t & 63, w = t >> 6;
    const int wr = w >> 2, wc = w & 3;
    const int l15 = lane & 15, l4 = lane >> 4;
    const int row0 = blockIdx.x * 128;

    i32x4 acc[4][8];
    #pragma unroll
    for (int m = 0; m < 4; ++m)
        #pragma unroll
        for (int n = 0; n < 8; ++n) acc[m][n] = (i32x4){0, 0, 0, 0};

    const int lr = lane >> 3;
    const int lcb = ((lane & 7) ^ lr) * 16;
    const signed char* Ab = A + (size_t)(row0 + lr) * 512 + lcb;
    const signed char* Bb = B + (size_t)lr * 512 + lcb;

    #pragma unroll
    for (int i = 0; i < 2; ++i) {
        int ch = w * 2 + i;
        gld16(Ab + (size_t)ch * 8 * 512, &As[0][ch * 1024]);
    }

    int cur = 0;
    for (int tt = 0; tt < NT; ++tt) {
        #pragma unroll
        for (int i = 0; i < 8; ++i) {
            int ch = w * 8 + i;
            gld16(Bb + (size_t)ch * 8 * 512 + tt * 128, &Bs[ch * 1024]);
        }
        SCHEDB();
        int tn = (tt + 1 < NT) ? tt + 1 : tt;
        #pragma unroll
        for (int i = 0; i < 2; ++i) {
            int ch = w * 2 + i;
            gld16(Ab + (size_t)ch * 8 * 512 + tn * 128, &As[cur ^ 1][ch * 1024]);
        }
        SCHEDB();
        asm volatile("s_waitcnt vmcnt(2)" ::: "memory");
        SBAR();

        #pragma unroll
        for (int kk = 0; kk < 2; ++kk) {
            int sl = kk * 4 + l4;
            int slw = (sl ^ (lane & 7)) * 16;
            i32x4 af[4], bf[8];
            #pragma unroll
            for (int m = 0; m < 4; ++m)
                af[m] = *reinterpret_cast<const i32x4*>(&As[cur][(wr * 64 + m * 16 + l15) * 128 + slw]);
            #pragma unroll
            for (int n = 0; n < 8; ++n)
                bf[n] = *reinterpret_cast<const i32x4*>(&Bs[(wc * 128 + n * 16 + l15) * 128 + slw]);
            #pragma unroll
            for (int m = 0; m < 4; ++m)
                #pragma unroll
                for (int n = 0; n < 8; ++n)
                    acc[m][n] = MFMAI8(af[m], bf[n], acc[m][n]);
        }

        SBAR();
        cur ^= 1;
    }

    double cs = (double)s1p[0] * (double)(wmax[0] / 7.0f + 1e-8f);
    double s2v = (double)s2p[0];
    #pragma unroll
    for (int m = 0; m < 4; ++m)
        #pragma unroll
        for (int n = 0; n < 8; ++n)
            #pragma unroll
            for (int j = 0; j < 4; ++j) {
                int row = row0 + wr * 64 + m * 16 + l4 * 4 + j;
                int col = wc * 128 + n * 16 + l15;
                double r = fmax((double)acc[m][n][j] * cs, 0.0) / s2v;
                double qv = fmin(rint(r), 15.0);
                A2[(size_t)row * 512 + col] = (signed char)qv;
                double fr = r - floor(r);
                if (fabs(fr - 0.5) < (double)FLAG_TOL && r < 16.0) {
                    int p = atomicAdd(flagCnt, 1);
                    if (p < FLAG_CAP) flagList[p] = (unsigned)(row * 512 + col);
                }
            }
}

// ---------------- fixups: BLAS-replicating sequential fp32 FMA ----------------

__global__ void k_fixup1(const float* __restrict__ X, const float* __restrict__ W1dq,
                         const float* __restrict__ s1p,
                         const int* __restrict__ flagCnt, const unsigned* __restrict__ flagList,
                         signed char* __restrict__ A1)
{
    int tid = blockIdx.x * blockDim.x + threadIdx.x;
    int nthr = gridDim.x * blockDim.x;
    int n = flagCnt[0];
    if (n > FLAG_CAP) n = FLAG_CAP;
    float s1 = s1p[0];
    for (int i = tid; i < n; i += nthr) {
        unsigned idx = flagList[i];
        int row = (int)(idx >> 9), col = (int)(idx & 511);
        const float* xr = X + (size_t)row * 784;
        const float* wr = W1dq + (size_t)col * 784;
        float acc = 0.f;
        for (int k = 0; k < 784; ++k)
            acc = fmaf(xr[k], wr[k], acc);       // k-ascending, single acc: BLAS order
        float tq = fmaxf(acc, 0.f) / s1;
        float code = fminf(rintf(tq), 15.f);
        A1[(size_t)row * 512 + col] = (signed char)code;
    }
}

__global__ void k_fixup2(const signed char* __restrict__ A1, const float* __restrict__ W2dq,
                         const float* __restrict__ s1p, const float* __restrict__ s2p,
                         const int* __restrict__ flagCnt, const unsigned* __restrict__ flagList,
                         signed char* __restrict__ A2)
{
    int tid = blockIdx.x * blockDim.x + threadIdx.x;
    int nthr = gridDim.x * blockDim.x;
    int n = flagCnt[0];
    if (n > FLAG_CAP) n = FLAG_CAP;
    float s1 = s1p[0], s2 = s2p[0];
    for (int i = tid; i < n; i += nthr) {
        unsigned idx = flagList[i];
        int row = (int)(idx >> 9), col = (int)(idx & 511);
        const signed char* ar = A1 + (size_t)row * 512;
        const float* wr = W2dq + (size_t)col * 512;
        float acc = 0.f;
        for (int k = 0; k < 512; ++k) {
            float adq = (float)ar[k] * s1;       // fp32 dequant, == ref
            acc = fmaf(adq, wr[k], acc);
        }
        float tq = fmaxf(acc, 0.f) / s2;
        float code = fminf(rintf(tq), 15.f);
        A2[(size_t)row * 512 + col] = (signed char)code;
    }
}

// ---------------- GEMM3: int8 [65536,512] @ [16,512]^T -> fp32 logits ----------------

__global__ __launch_bounds__(256) void k_gemm3i(
    const signed char* __restrict__ A2, const signed char* __restrict__ Q3,
    const float* __restrict__ wmax, const float* __restrict__ s2p,
    float* __restrict__ Out)
{
    __shared__ __align__(16) signed char As[256][80];
    __shared__ __align__(16) signed char Bs[16][80];

    const int t = threadIdx.x;
    const int row0 = blockIdx.x * 256;
    const int lane = t & 63, wv = t >> 6;

    i32x4 acc[4];
    #pragma unroll
    for (int m = 0; m < 4; ++m) acc[m] = (i32x4){0, 0, 0, 0};

    for (int k0 = 0; k0 < 512; k0 += 64) {
        #pragma unroll
        for (int i = 0; i < 4; ++i) {
            int f = t + 256 * i;
            int r = f >> 2, c = f & 3;
            *reinterpret_cast<uint4*>(&As[r][c * 16]) =
                *reinterpret_cast<const uint4*>(A2 + (size_t)(row0 + r) * 512 + k0 + c * 16);
        }
        if (t < 64) {
            int r = t >> 2, c = t & 3;
            *reinterpret_cast<uint4*>(&Bs[r][c * 16]) =
                *reinterpret_cast<const uint4*>(Q3 + (size_t)r * 512 + k0 + c * 16);
        }
        __syncthreads();

        i32x4 bf = *reinterpret_cast<const i32x4*>(&Bs[lane & 15][(lane >> 4) * 16]);
        #pragma unroll
        for (int m = 0; m < 4; ++m) {
            i32x4 af = *reinterpret_cast<const i32x4*>(&As[wv * 64 + m * 16 + (lane & 15)][(lane >> 4) * 16]);
            acc[m] = MFMAI8(af, bf, acc[m]);
        }
        __syncthreads();
    }

    double cs = (double)s2p[0] * (double)(wmax[0] / 7.0f + 1e-8f);
    #pragma unroll
    for (int m = 0; m < 4; ++m)
        #pragma unroll
        for (int j = 0; j < 4; ++j) {
            int row = row0 + wv * 64 + m * 16 + (lane >> 4) * 4 + j;
            int col = lane & 15;
            if (col < 10)
                Out[(size_t)row * 10 + col] = (float)((double)acc[m][j] * cs);
        }
}

// ---------------- launch ----------------

extern "C" void kernel_launch(void* const* d_in, const int* in_sizes, int n_in,
                              void* d_out, int out_size, void* d_ws, size_t ws_size,
                              hipStream_t stream)
{
    (void)in_sizes; (void)n_in; (void)out_size; (void)ws_size;

    const float* X  = (const float*)d_in[0];
    const float* W1 = (const float*)d_in[1];
    const float* W2 = (const float*)d_in[2];
    const float* W3 = (const float*)d_in[3];
    const float* s1 = (const float*)d_in[4];
    const float* s2 = (const float*)d_in[5];
    float* Out = (float*)d_out;

    char* ws = (char*)d_ws;
    float* maxes     = (float*)ws;
    int*   cnts      = (int*)(ws + 16);
    f16*   q1h       = (f16*)(ws + (size_t)(1u << 20));              // 852992 B
    float* w1dq      = (float*)(ws + (size_t)(2u << 20));            // 1605632 B
    float* w2dq      = (float*)(ws + (size_t)(4u << 20));            // 1048576 B
    signed char* q2i = (signed char*)(ws + (size_t)(6u << 20));      // 262144 B
    signed char* q3i = (signed char*)(ws + (size_t)(6u << 20) + 300000);  // 8192 B
    signed char* a1  = (signed char*)(ws + (size_t)(8u << 20));      // 32 MB
    signed char* a2  = (signed char*)(ws + (size_t)(40u << 20));     // 32 MB
    unsigned* fl1    = (unsigned*)(ws + (size_t)(72u << 20));        // 4 MB
    unsigned* fl2    = (unsigned*)(ws + (size_t)(76u << 20));        // 4 MB

    k_zero<<<1, 64, 0, stream>>>(maxes, cnts);
    k_absmax<<<256, 256, 0, stream>>>(W1, 512 * 784, maxes + 0);
    k_absmax<<<256, 256, 0, stream>>>(W2, 512 * 512, maxes + 1);
    k_absmax<<<8, 256, 0, stream>>>(W3, 10 * 512, maxes + 2);
    k_quantw1<<<(512 * 832 + 255) / 256, 256, 0, stream>>>(W1, maxes + 0, w1dq, q1h);
    k_quantw2<<<(512 * 512 + 255) / 256, 256, 0, stream>>>(W2, maxes + 1, q2i, w2dq, 512 * 512);
    k_quantw3<<<(16 * 512 + 255) / 256, 256, 0, stream>>>(W3, maxes + 2, q3i);

    k_gemm1W2<<<4096, 256, 0, stream>>>(X, q1h, maxes + 0, s1, a1, cnts + 0, fl1);
    k_fixup1<<<512, 256, 0, stream>>>(X, w1dq, s1, cnts + 0, fl1, a1);
    k_gemm2F<<<512, 512, 0, stream>>>(a1, q2i, maxes + 1, s1, s2, a2, cnts + 1, fl2);
    k_fixup2<<<512, 256, 0, stream>>>(a1, w2dq, s1, s2, cnts + 1, fl2, a2);
    k_gemm3i<<<256, 256, 0, stream>>>(a2, q3i, maxes + 2, s2, Out);
}

// Round 17
// 583.635 us; speedup vs baseline: 2.1464x; 1.0039x over previous
//
#include <hip/hip_runtime.h>
#include <hip/hip_fp16.h>

typedef _Float16 f16;
typedef _Float16 f16x4 __attribute__((ext_vector_type(4)));
typedef _Float16 f16x8 __attribute__((ext_vector_type(8)));
typedef float f32x4 __attribute__((ext_vector_type(4)));
typedef int i32x4 __attribute__((ext_vector_type(4)));

#define MFMA16(a, b, c) __builtin_amdgcn_mfma_f32_16x16x32_f16((a), (b), (c), 0, 0, 0)
#define MFMAI8(a, b, c) __builtin_amdgcn_mfma_i32_16x16x64_i8((a), (b), (c), 0, 0, 0)

#define FLAG_CAP (1024 * 1024)
#define FLAG_TOL 1e-3f

#define SBAR()   __builtin_amdgcn_s_barrier()
#define SCHEDB() __builtin_amdgcn_sched_barrier(0)

// async global->LDS, 16 B per lane (used by gemm2F).
__device__ __forceinline__ void gld16(const void* g, void* l) {
    __builtin_amdgcn_global_load_lds(
        (const __attribute__((address_space(1))) unsigned int*)g,
        (__attribute__((address_space(3))) unsigned int*)l,
        16, 0, 0);
}

// ---------------- scale computation ----------------

__global__ void k_zero(float* p, int* cnt) {
    if (threadIdx.x < 3) p[threadIdx.x] = 0.f;
    if (threadIdx.x == 3) { cnt[0] = 0; cnt[1] = 0; }
}

__global__ void k_absmax(const float* __restrict__ w, int n, float* __restrict__ out) {
    float m = 0.f;
    int stride = gridDim.x * blockDim.x;
    for (int i = blockIdx.x * blockDim.x + threadIdx.x; i < n; i += stride)
        m = fmaxf(m, fabsf(w[i]));
    #pragma unroll
    for (int o = 32; o > 0; o >>= 1) m = fmaxf(m, __shfl_down(m, o));
    __shared__ float sm[4];
    int lane = threadIdx.x & 63, wv = threadIdx.x >> 6;
    if (lane == 0) sm[wv] = m;
    __syncthreads();
    if (threadIdx.x == 0) {
        float mm = fmaxf(fmaxf(sm[0], sm[1]), fmaxf(sm[2], sm[3]));
        atomicMax((unsigned int*)out, __float_as_uint(mm));  // nonneg floats only
    }
}

// W1: fp32 dequant w1dq (fixup) + padded f16 panel q1h [512][832]
__global__ void k_quantw1(const float* __restrict__ w, const float* __restrict__ wmax,
                          float* __restrict__ wdq, f16* __restrict__ q1h) {
    int i = blockIdx.x * blockDim.x + threadIdx.x;
    if (i >= 512 * 832) return;
    int n = i / 832, k = i - n * 832;
    float v = 0.f;
    if (k < 784) {
        float s = wmax[0] / 7.0f + 1e-8f;
        v = rintf(w[n * 784 + k] / s);       // fp32 ops replicate numpy semantics
        v = fminf(fmaxf(v, -7.f), 7.f);
        wdq[n * 784 + k] = v * s;
    }
    q1h[(size_t)n * 832 + k] = (f16)v;
}

// W2: int8 codes + fp32 dequant (fixup)
__global__ void k_quantw2(const float* __restrict__ w, const float* __restrict__ wmax,
                          signed char* __restrict__ q, float* __restrict__ wdq, int n) {
    float s = wmax[0] / 7.0f + 1e-8f;
    int i = blockIdx.x * blockDim.x + threadIdx.x;
    if (i < n) {
        float v = rintf(w[i] / s);
        v = fminf(fmaxf(v, -7.f), 7.f);
        q[i] = (signed char)v;
        if (wdq) wdq[i] = v * s;
    }
}

// W3: int8, zero-padded to 16x512
__global__ void k_quantw3(const float* __restrict__ w, const float* __restrict__ wmax,
                          signed char* __restrict__ q) {
    float s = wmax[0] / 7.0f + 1e-8f;
    int i = blockIdx.x * blockDim.x + threadIdx.x;
    if (i < 16 * 512) {
        float v = 0.f;
        if (i < 10 * 512) {
            v = rintf(w[i] / s);
            v = fminf(fmaxf(v, -7.f), 7.f);
        }
        q[i] = (signed char)v;
    }
}

// ========== GEMM1 "W3": wave-autonomous, zero LDS/barriers, LOOKAHEAD-2 ==========
// Wave tile 32x64: acc[2][4] = 32 AGPR. THREE named register sets -> 16 loads
// in flight per wave (2 K-tiles ahead) — 2x the memory-level parallelism of
// round 16. ~148 regs/wave -> __launch_bounds__(256,3) caps 170 (12 waves/CU).
// LOAD clamps the tile index (clamped prefetches hit valid memory, never used).

__global__ __launch_bounds__(256, 3) void k_gemm1W3(
    const float* __restrict__ X, const f16* __restrict__ B,
    const float* __restrict__ wmax, const float* __restrict__ s1p,
    signed char* __restrict__ A1, int* __restrict__ flagCnt, unsigned* __restrict__ flagList)
{
    constexpr int NT = 25;                       // ceil(784/32); tiles >=784 are zero
    const int t = threadIdx.x;
    const int lane = t & 63, w = t >> 6;         // 4 waves
    const int l15 = lane & 15, l4 = lane >> 4;

    // chunked XCD swizzle: consecutive lg (same XCD) cover the 4 col-groups
    // of one 64-row panel -> X panel served once per XCD L2
    const int bid = blockIdx.x;                  // 4096 blocks
    const int lg = (bid & 7) * 512 + (bid >> 3);
    const int rowg = lg >> 2, colg = lg & 3;
    const int row0 = rowg * 64 + (w >> 1) * 32;  // wave M-base (32 rows)
    const int col0 = colg * 128 + (w & 1) * 64;  // wave N-base (64 cols)

    f32x4 acc[2][4];
    #pragma unroll
    for (int m = 0; m < 2; ++m)
        #pragma unroll
        for (int n = 0; n < 4; ++n) acc[m][n] = (f32x4){0.f, 0.f, 0.f, 0.f};

    const float* Xb = X + (size_t)(row0 + l15) * 784 + l4 * 8;
    const f16*   Bb = B + (size_t)(col0 + l15) * 832 + l4 * 8;

    struct Set { float4 x[2][2]; f16x8 b[4]; };
    Set s0, s1, s2;

    auto LOAD = [&](Set& s, int tn) {
        if (tn > NT - 1) tn = NT - 1;            // clamp: valid mem, never consumed
        const int k0 = tn * 32;
        #pragma unroll
        for (int m = 0; m < 2; ++m)
            #pragma unroll
            for (int i = 0; i < 2; ++i) {
                int gk = k0 + l4 * 8 + i * 4;            // multiple of 4
                s.x[m][i] = make_float4(0.f, 0.f, 0.f, 0.f);
                if (gk < 784)
                    s.x[m][i] = *reinterpret_cast<const float4*>(
                        Xb + (size_t)m * 16 * 784 + k0 + i * 4);
            }
        #pragma unroll
        for (int n = 0; n < 4; ++n)                      // B padded to 832: no pred
            s.b[n] = *reinterpret_cast<const f16x8*>(Bb + (size_t)n * 16 * 832 + k0);
    };

    auto COMP = [&](Set& s) {
        f16x8 ah[2], al[2];
        #pragma unroll
        for (int m = 0; m < 2; ++m)
            #pragma unroll
            for (int i = 0; i < 2; ++i) {
                float vv[4] = {s.x[m][i].x, s.x[m][i].y, s.x[m][i].z, s.x[m][i].w};
                #pragma unroll
                for (int j = 0; j < 4; ++j) {
                    f16 c0 = (f16)vv[j];                 // RNE
                    ah[m][i * 4 + j] = c0;
                    al[m][i * 4 + j] = (f16)(vv[j] - (float)c0);  // exact residual
                }
            }
        #pragma unroll
        for (int m = 0; m < 2; ++m)
            #pragma unroll
            for (int n = 0; n < 4; ++n) {                // same per-output order as r9-16
                acc[m][n] = MFMA16(ah[m], s.b[n], acc[m][n]);
                acc[m][n] = MFMA16(al[m], s.b[n], acc[m][n]);
            }
    };

    // pipeline: lookahead 2 (16 loads in flight)
    LOAD(s0, 0);
    LOAD(s1, 1);
    // 8 triples cover tiles 0..23; tile 24 computed in the tail from s0
    for (int i = 0; i < 8; ++i) {
        const int b = 3 * i;
        LOAD(s2, b + 2);  COMP(s0);      // tile b
        LOAD(s0, b + 3);  COMP(s1);      // tile b+1
        LOAD(s1, b + 4);  COMP(s2);      // tile b+2
    }
    COMP(s0);                            // tile 24

    float sw = wmax[0] / 7.0f + 1e-8f;
    float s1v = s1p[0];
    #pragma unroll
    for (int m = 0; m < 2; ++m)
        #pragma unroll
        for (int n = 0; n < 4; ++n)
            #pragma unroll
            for (int j = 0; j < 4; ++j) {
                int row = row0 + m * 16 + l4 * 4 + j;
                int col = col0 + n * 16 + l15;
                float h = sw * acc[m][n][j];
                float r = fmaxf(h, 0.f) / s1v;
                float qv = fminf(rintf(r), 15.f);
                A1[(size_t)row * 512 + col] = (signed char)qv;
                float fr = r - floorf(r);
                if (fabsf(fr - 0.5f) < FLAG_TOL) {
                    int p = atomicAdd(flagCnt, 1);
                    if (p < FLAG_CAP) flagList[p] = (unsigned)(row * 512 + col);
                }
            }
}

// ========== GEMM2: full-N i8 block (128 x 512), K=512 (unchanged) ==========

__global__ __launch_bounds__(512, 2) void k_gemm2F(
    const signed char* __restrict__ A, const signed char* __restrict__ B,
    const float* __restrict__ wmax, const float* __restrict__ s1p, const float* __restrict__ s2p,
    signed char* __restrict__ A2, int* __restrict__ flagCnt, unsigned* __restrict__ flagList)
{
    constexpr int NT = 4;
    __shared__ __align__(16) signed char As[2][128 * 128];
    __shared__ __align__(16) signed char Bs[512 * 128];

    const int t = threadIdx.x;
    const int lane = t & 63, w = t >> 6;
    const int wr = w >> 2, wc = w & 3;
    const int l15 = lane & 15, l4 = lane >> 4;
    const int row0 = blockIdx.x * 128;

    i32x4 acc[4][8];
    #pragma unroll
    for (int m = 0; m < 4; ++m)
        #pragma unroll
        for (int n = 0; n < 8; ++n) acc[m][n] = (i32x4){0, 0, 0, 0};

    const int lr = lane >> 3;
    const int lcb = ((lane & 7) ^ lr) * 16;
    const signed char* Ab = A + (size_t)(row0 + lr) * 512 + lcb;
    const signed char* Bb = B + (size_t)lr * 512 + lcb;

    #pragma unroll
    for (int i = 0; i < 2; ++i) {
        int ch = w * 2 + i;
        gld16(Ab + (size_t)ch * 8 * 512, &As[0][ch * 1024]);
    }

    int cur = 0;
    for (int tt = 0; tt < NT; ++tt) {
        #pragma unroll
        for (int i = 0; i < 8; ++i) {
            int ch = w * 8 + i;
            gld16(Bb + (size_t)ch * 8 * 512 + tt * 128, &Bs[ch * 1024]);
        }
        SCHEDB();
        int tn = (tt + 1 < NT) ? tt + 1 : tt;
        #pragma unroll
        for (int i = 0; i < 2; ++i) {
            int ch = w * 2 + i;
            gld16(Ab + (size_t)ch * 8 * 512 + tn * 128, &As[cur ^ 1][ch * 1024]);
        }
        SCHEDB();
        asm volatile("s_waitcnt vmcnt(2)" ::: "memory");
        SBAR();

        #pragma unroll
        for (int kk = 0; kk < 2; ++kk) {
            int sl = kk * 4 + l4;
            int slw = (sl ^ (lane & 7)) * 16;
            i32x4 af[4], bf[8];
            #pragma unroll
            for (int m = 0; m < 4; ++m)
                af[m] = *reinterpret_cast<const i32x4*>(&As[cur][(wr * 64 + m * 16 + l15) * 128 + slw]);
            #pragma unroll
            for (int n = 0; n < 8; ++n)
                bf[n] = *reinterpret_cast<const i32x4*>(&Bs[(wc * 128 + n * 16 + l15) * 128 + slw]);
            #pragma unroll
            for (int m = 0; m < 4; ++m)
                #pragma unroll
                for (int n = 0; n < 8; ++n)
                    acc[m][n] = MFMAI8(af[m], bf[n], acc[m][n]);
        }

        SBAR();
        cur ^= 1;
    }

    double cs = (double)s1p[0] * (double)(wmax[0] / 7.0f + 1e-8f);
    double s2v = (double)s2p[0];
    #pragma unroll
    for (int m = 0; m < 4; ++m)
        #pragma unroll
        for (int n = 0; n < 8; ++n)
            #pragma unroll
            for (int j = 0; j < 4; ++j) {
                int row = row0 + wr * 64 + m * 16 + l4 * 4 + j;
                int col = wc * 128 + n * 16 + l15;
                double r = fmax((double)acc[m][n][j] * cs, 0.0) / s2v;
                double qv = fmin(rint(r), 15.0);
                A2[(size_t)row * 512 + col] = (signed char)qv;
                double fr = r - floor(r);
                if (fabs(fr - 0.5) < (double)FLAG_TOL && r < 16.0) {
                    int p = atomicAdd(flagCnt, 1);
                    if (p < FLAG_CAP) flagList[p] = (unsigned)(row * 512 + col);
                }
            }
}

// ---------------- fixups: BLAS-replicating sequential fp32 FMA ----------------

__global__ void k_fixup1(const float* __restrict__ X, const float* __restrict__ W1dq,
                         const float* __restrict__ s1p,
                         const int* __restrict__ flagCnt, const unsigned* __restrict__ flagList,
                         signed char* __restrict__ A1)
{
    int tid = blockIdx.x * blockDim.x + threadIdx.x;
    int nthr = gridDim.x * blockDim.x;
    int n = flagCnt[0];
    if (n > FLAG_CAP) n = FLAG_CAP;
    float s1 = s1p[0];
    for (int i = tid; i < n; i += nthr) {
        unsigned idx = flagList[i];
        int row = (int)(idx >> 9), col = (int)(idx & 511);
        const float* xr = X + (size_t)row * 784;
        const float* wr = W1dq + (size_t)col * 784;
        float acc = 0.f;
        for (int k = 0; k < 784; ++k)
            acc = fmaf(xr[k], wr[k], acc);       // k-ascending, single acc: BLAS order
        float tq = fmaxf(acc, 0.f) / s1;
        float code = fminf(rintf(tq), 15.f);
        A1[(size_t)row * 512 + col] = (signed char)code;
    }
}

__global__ void k_fixup2(const signed char* __restrict__ A1, const float* __restrict__ W2dq,
                         const float* __restrict__ s1p, const float* __restrict__ s2p,
                         const int* __restrict__ flagCnt, const unsigned* __restrict__ flagList,
                         signed char* __restrict__ A2)
{
    int tid = blockIdx.x * blockDim.x + threadIdx.x;
    int nthr = gridDim.x * blockDim.x;
    int n = flagCnt[0];
    if (n > FLAG_CAP) n = FLAG_CAP;
    float s1 = s1p[0], s2 = s2p[0];
    for (int i = tid; i < n; i += nthr) {
        unsigned idx = flagList[i];
        int row = (int)(idx >> 9), col = (int)(idx & 511);
        const signed char* ar = A1 + (size_t)row * 512;
        const float* wr = W2dq + (size_t)col * 512;
        float acc = 0.f;
        for (int k = 0; k < 512; ++k) {
            float adq = (float)ar[k] * s1;       // fp32 dequant, == ref
            acc = fmaf(adq, wr[k], acc);
        }
        float tq = fmaxf(acc, 0.f) / s2;
        float code = fminf(rintf(tq), 15.f);
        A2[(size_t)row * 512 + col] = (signed char)code;
    }
}

// ---------------- GEMM3: int8 [65536,512] @ [16,512]^T -> fp32 logits ----------------

__global__ __launch_bounds__(256) void k_gemm3i(
    const signed char* __restrict__ A2, const signed char* __restrict__ Q3,
    const float* __restrict__ wmax, const float* __restrict__ s2p,
    float* __restrict__ Out)
{
    __shared__ __align__(16) signed char As[256][80];
    __shared__ __align__(16) signed char Bs[16][80];

    const int t = threadIdx.x;
    const int row0 = blockIdx.x * 256;
    const int lane = t & 63, wv = t >> 6;

    i32x4 acc[4];
    #pragma unroll
    for (int m = 0; m < 4; ++m) acc[m] = (i32x4){0, 0, 0, 0};

    for (int k0 = 0; k0 < 512; k0 += 64) {
        #pragma unroll
        for (int i = 0; i < 4; ++i) {
            int f = t + 256 * i;
            int r = f >> 2, c = f & 3;
            *reinterpret_cast<uint4*>(&As[r][c * 16]) =
                *reinterpret_cast<const uint4*>(A2 + (size_t)(row0 + r) * 512 + k0 + c * 16);
        }
        if (t < 64) {
            int r = t >> 2, c = t & 3;
            *reinterpret_cast<uint4*>(&Bs[r][c * 16]) =
                *reinterpret_cast<const uint4*>(Q3 + (size_t)r * 512 + k0 + c * 16);
        }
        __syncthreads();

        i32x4 bf = *reinterpret_cast<const i32x4*>(&Bs[lane & 15][(lane >> 4) * 16]);
        #pragma unroll
        for (int m = 0; m < 4; ++m) {
            i32x4 af = *reinterpret_cast<const i32x4*>(&As[wv * 64 + m * 16 + (lane & 15)][(lane >> 4) * 16]);
            acc[m] = MFMAI8(af, bf, acc[m]);
        }
        __syncthreads();
    }

    double cs = (double)s2p[0] * (double)(wmax[0] / 7.0f + 1e-8f);
    #pragma unroll
    for (int m = 0; m < 4; ++m)
        #pragma unroll
        for (int j = 0; j < 4; ++j) {
            int row = row0 + wv * 64 + m * 16 + (lane >> 4) * 4 + j;
            int col = lane & 15;
            if (col < 10)
                Out[(size_t)row * 10 + col] = (float)((double)acc[m][j] * cs);
        }
}

// ---------------- launch ----------------

extern "C" void kernel_launch(void* const* d_in, const int* in_sizes, int n_in,
                              void* d_out, int out_size, void* d_ws, size_t ws_size,
                              hipStream_t stream)
{
    (void)in_sizes; (void)n_in; (void)out_size; (void)ws_size;

    const float* X  = (const float*)d_in[0];
    const float* W1 = (const float*)d_in[1];
    const float* W2 = (const float*)d_in[2];
    const float* W3 = (const float*)d_in[3];
    const float* s1 = (const float*)d_in[4];
    const float* s2 = (const float*)d_in[5];
    float* Out = (float*)d_out;

    char* ws = (char*)d_ws;
    float* maxes     = (float*)ws;
    int*   cnts      = (int*)(ws + 16);
    f16*   q1h       = (f16*)(ws + (size_t)(1u << 20));              // 852992 B
    float* w1dq      = (float*)(ws + (size_t)(2u << 20));            // 1605632 B
    float* w2dq      = (float*)(ws + (size_t)(4u << 20));            // 1048576 B
    signed char* q2i = (signed char*)(ws + (size_t)(6u << 20));      // 262144 B
    signed char* q3i = (signed char*)(ws + (size_t)(6u << 20) + 300000);  // 8192 B
    signed char* a1  = (signed char*)(ws + (size_t)(8u << 20));      // 32 MB
    signed char* a2  = (signed char*)(ws + (size_t)(40u << 20));     // 32 MB
    unsigned* fl1    = (unsigned*)(ws + (size_t)(72u << 20));        // 4 MB
    unsigned* fl2    = (unsigned*)(ws + (size_t)(76u << 20));        // 4 MB

    k_zero<<<1, 64, 0, stream>>>(maxes, cnts);
    k_absmax<<<256, 256, 0, stream>>>(W1, 512 * 784, maxes + 0);
    k_absmax<<<256, 256, 0, stream>>>(W2, 512 * 512, maxes + 1);
    k_absmax<<<8, 256, 0, stream>>>(W3, 10 * 512, maxes + 2);
    k_quantw1<<<(512 * 832 + 255) / 256, 256, 0, stream>>>(W1, maxes + 0, w1dq, q1h);
    k_quantw2<<<(512 * 512 + 255) / 256, 256, 0, stream>>>(W2, maxes + 1, q2i, w2dq, 512 * 512);
    k_quantw3<<<(16 * 512 + 255) / 256, 256, 0, stream>>>(W3, maxes + 2, q3i);

    k_gemm1W3<<<4096, 256, 0, stream>>>(X, q1h, maxes + 0, s1, a1, cnts + 0, fl1);
    k_fixup1<<<512, 256, 0, stream>>>(X, w1dq, s1, cnts + 0, fl1, a1);
    k_gemm2F<<<512, 512, 0, stream>>>(a1, q2i, maxes + 1, s1, s2, a2, cnts + 1, fl2);
    k_fixup2<<<512, 256, 0, stream>>>(a1, w2dq, s1, s2, cnts + 1, fl2, a2);
    k_gemm3i<<<256, 256, 0, stream>>>(a2, q3i, maxes + 2, s2, Out);
}

// Round 18
// 569.718 us; speedup vs baseline: 2.1988x; 1.0244x over previous
//
#include <hip/hip_runtime.h>
#include <hip/hip_fp16.h>

typedef _Float16 f16;
typedef _Float16 f16x4 __attribute__((ext_vector_type(4)));
typedef _Float16 f16x8 __attribute__((ext_vector_type(8)));
typedef float f32x4 __attribute__((ext_vector_type(4)));
typedef int i32x4 __attribute__((ext_vector_type(4)));

#define MFMA16(a, b, c) __builtin_amdgcn_mfma_f32_16x16x32_f16((a), (b), (c), 0, 0, 0)
#define MFMAI8(a, b, c) __builtin_amdgcn_mfma_i32_16x16x64_i8((a), (b), (c), 0, 0, 0)

#define FLAG_CAP (1024 * 1024)
#define FLAG_TOL 1e-3f

#define SBAR()   __builtin_amdgcn_s_barrier()
#define SCHEDB() __builtin_amdgcn_sched_barrier(0)

// async global->LDS, 16 B per lane (used by gemm2F).
__device__ __forceinline__ void gld16(const void* g, void* l) {
    __builtin_amdgcn_global_load_lds(
        (const __attribute__((address_space(1))) unsigned int*)g,
        (__attribute__((address_space(3))) unsigned int*)l,
        16, 0, 0);
}

// ---------------- prologue: zero, fused absmax, fused quant ----------------

__global__ void k_zero(float* p, int* cnt) {
    if (threadIdx.x < 3) p[threadIdx.x] = 0.f;
    if (threadIdx.x == 3) { cnt[0] = 0; cnt[1] = 0; }
}

// one launch, three segments: blocks [0,256) -> W1, [256,512) -> W2, [512,520) -> W3
__global__ void k_absmax3(const float* __restrict__ W1, const float* __restrict__ W2,
                          const float* __restrict__ W3, float* __restrict__ maxes) {
    const float* w; int n; float* out; int nb, b0;
    int b = blockIdx.x;
    if (b < 256)      { w = W1; n = 512 * 784; out = maxes + 0; nb = 256; b0 = 0;   }
    else if (b < 512) { w = W2; n = 512 * 512; out = maxes + 1; nb = 256; b0 = 256; }
    else              { w = W3; n = 10 * 512;  out = maxes + 2; nb = 8;   b0 = 512; }
    int lb = b - b0;
    float m = 0.f;
    int stride = nb * blockDim.x;
    for (int i = lb * blockDim.x + threadIdx.x; i < n; i += stride)
        m = fmaxf(m, fabsf(w[i]));
    #pragma unroll
    for (int o = 32; o > 0; o >>= 1) m = fmaxf(m, __shfl_down(m, o));
    __shared__ float sm[4];
    int lane = threadIdx.x & 63, wv = threadIdx.x >> 6;
    if (lane == 0) sm[wv] = m;
    __syncthreads();
    if (threadIdx.x == 0) {
        float mm = fmaxf(fmaxf(sm[0], sm[1]), fmaxf(sm[2], sm[3]));
        atomicMax((unsigned int*)out, __float_as_uint(mm));  // nonneg floats only
    }
}

// one launch, three segments (fp32 ops replicate numpy semantics exactly):
//  blocks [0,1664):   W1 -> q1h [512][832] f16 (pad) + w1dq fp32
//  blocks [1664,2688): W2 -> q2i int8 + w2dq fp32
//  blocks [2688,2720): W3 -> q3i int8, padded to 16x512
__global__ void k_quant_all(const float* __restrict__ W1, const float* __restrict__ W2,
                            const float* __restrict__ W3, const float* __restrict__ maxes,
                            f16* __restrict__ q1h, float* __restrict__ w1dq,
                            signed char* __restrict__ q2i, float* __restrict__ w2dq,
                            signed char* __restrict__ q3i) {
    int b = blockIdx.x;
    if (b < 1664) {
        int i = b * 256 + threadIdx.x;
        if (i >= 512 * 832) return;
        int n = i / 832, k = i - n * 832;
        float v = 0.f;
        if (k < 784) {
            float s = maxes[0] / 7.0f + 1e-8f;
            v = rintf(W1[n * 784 + k] / s);
            v = fminf(fmaxf(v, -7.f), 7.f);
            w1dq[n * 784 + k] = v * s;
        }
        q1h[(size_t)n * 832 + k] = (f16)v;
    } else if (b < 2688) {
        int i = (b - 1664) * 256 + threadIdx.x;   // all < 262144 valid
        float s = maxes[1] / 7.0f + 1e-8f;
        float v = rintf(W2[i] / s);
        v = fminf(fmaxf(v, -7.f), 7.f);
        q2i[i] = (signed char)v;
        w2dq[i] = v * s;
    } else {
        int i = (b - 2688) * 256 + threadIdx.x;
        if (i >= 16 * 512) return;
        float v = 0.f;
        if (i < 10 * 512) {
            float s = maxes[2] / 7.0f + 1e-8f;
            v = rintf(W3[i] / s);
            v = fminf(fmaxf(v, -7.f), 7.f);
        }
        q3i[i] = (signed char)v;
    }
}

// ========== GEMM1 "W3": wave-autonomous, zero LDS/barriers, LOOKAHEAD-2 ==========
// (unchanged from round 17 — best measured: 433 us)

__global__ __launch_bounds__(256, 3) void k_gemm1W3(
    const float* __restrict__ X, const f16* __restrict__ B,
    const float* __restrict__ wmax, const float* __restrict__ s1p,
    signed char* __restrict__ A1, int* __restrict__ flagCnt, unsigned* __restrict__ flagList)
{
    constexpr int NT = 25;                       // ceil(784/32); tiles >=784 are zero
    const int t = threadIdx.x;
    const int lane = t & 63, w = t >> 6;         // 4 waves
    const int l15 = lane & 15, l4 = lane >> 4;

    const int bid = blockIdx.x;                  // 4096 blocks
    const int lg = (bid & 7) * 512 + (bid >> 3);
    const int rowg = lg >> 2, colg = lg & 3;
    const int row0 = rowg * 64 + (w >> 1) * 32;  // wave M-base (32 rows)
    const int col0 = colg * 128 + (w & 1) * 64;  // wave N-base (64 cols)

    f32x4 acc[2][4];
    #pragma unroll
    for (int m = 0; m < 2; ++m)
        #pragma unroll
        for (int n = 0; n < 4; ++n) acc[m][n] = (f32x4){0.f, 0.f, 0.f, 0.f};

    const float* Xb = X + (size_t)(row0 + l15) * 784 + l4 * 8;
    const f16*   Bb = B + (size_t)(col0 + l15) * 832 + l4 * 8;

    struct Set { float4 x[2][2]; f16x8 b[4]; };
    Set s0, s1, s2;

    auto LOAD = [&](Set& s, int tn) {
        if (tn > NT - 1) tn = NT - 1;            // clamp: valid mem, never consumed
        const int k0 = tn * 32;
        #pragma unroll
        for (int m = 0; m < 2; ++m)
            #pragma unroll
            for (int i = 0; i < 2; ++i) {
                int gk = k0 + l4 * 8 + i * 4;            // multiple of 4
                s.x[m][i] = make_float4(0.f, 0.f, 0.f, 0.f);
                if (gk < 784)
                    s.x[m][i] = *reinterpret_cast<const float4*>(
                        Xb + (size_t)m * 16 * 784 + k0 + i * 4);
            }
        #pragma unroll
        for (int n = 0; n < 4; ++n)                      // B padded to 832: no pred
            s.b[n] = *reinterpret_cast<const f16x8*>(Bb + (size_t)n * 16 * 832 + k0);
    };

    auto COMP = [&](Set& s) {
        f16x8 ah[2], al[2];
        #pragma unroll
        for (int m = 0; m < 2; ++m)
            #pragma unroll
            for (int i = 0; i < 2; ++i) {
                float vv[4] = {s.x[m][i].x, s.x[m][i].y, s.x[m][i].z, s.x[m][i].w};
                #pragma unroll
                for (int j = 0; j < 4; ++j) {
                    f16 c0 = (f16)vv[j];                 // RNE
                    ah[m][i * 4 + j] = c0;
                    al[m][i * 4 + j] = (f16)(vv[j] - (float)c0);  // exact residual
                }
            }
        #pragma unroll
        for (int m = 0; m < 2; ++m)
            #pragma unroll
            for (int n = 0; n < 4; ++n) {                // same per-output order as r9-17
                acc[m][n] = MFMA16(ah[m], s.b[n], acc[m][n]);
                acc[m][n] = MFMA16(al[m], s.b[n], acc[m][n]);
            }
    };

    LOAD(s0, 0);
    LOAD(s1, 1);
    for (int i = 0; i < 8; ++i) {
        const int b = 3 * i;
        LOAD(s2, b + 2);  COMP(s0);      // tile b
        LOAD(s0, b + 3);  COMP(s1);      // tile b+1
        LOAD(s1, b + 4);  COMP(s2);      // tile b+2
    }
    COMP(s0);                            // tile 24

    float sw = wmax[0] / 7.0f + 1e-8f;
    float s1v = s1p[0];
    #pragma unroll
    for (int m = 0; m < 2; ++m)
        #pragma unroll
        for (int n = 0; n < 4; ++n)
            #pragma unroll
            for (int j = 0; j < 4; ++j) {
                int row = row0 + m * 16 + l4 * 4 + j;
                int col = col0 + n * 16 + l15;
                float h = sw * acc[m][n][j];
                float r = fmaxf(h, 0.f) / s1v;
                float qv = fminf(rintf(r), 15.f);
                A1[(size_t)row * 512 + col] = (signed char)qv;
                float fr = r - floorf(r);
                if (fabsf(fr - 0.5f) < FLAG_TOL) {
                    int p = atomicAdd(flagCnt, 1);
                    if (p < FLAG_CAP) flagList[p] = (unsigned)(row * 512 + col);
                }
            }
}

// ========== GEMM2: full-N i8 block (128 x 512), K=512 (unchanged) ==========

__global__ __launch_bounds__(512, 2) void k_gemm2F(
    const signed char* __restrict__ A, const signed char* __restrict__ B,
    const float* __restrict__ wmax, const float* __restrict__ s1p, const float* __restrict__ s2p,
    signed char* __restrict__ A2, int* __restrict__ flagCnt, unsigned* __restrict__ flagList)
{
    constexpr int NT = 4;
    __shared__ __align__(16) signed char As[2][128 * 128];
    __shared__ __align__(16) signed char Bs[512 * 128];

    const int t = threadIdx.x;
    const int lane = t & 63, w = t >> 6;
    const int wr = w >> 2, wc = w & 3;
    const int l15 = lane & 15, l4 = lane >> 4;
    const int row0 = blockIdx.x * 128;

    i32x4 acc[4][8];
    #pragma unroll
    for (int m = 0; m < 4; ++m)
        #pragma unroll
        for (int n = 0; n < 8; ++n) acc[m][n] = (i32x4){0, 0, 0, 0};

    const int lr = lane >> 3;
    const int lcb = ((lane & 7) ^ lr) * 16;
    const signed char* Ab = A + (size_t)(row0 + lr) * 512 + lcb;
    const signed char* Bb = B + (size_t)lr * 512 + lcb;

    #pragma unroll
    for (int i = 0; i < 2; ++i) {
        int ch = w * 2 + i;
        gld16(Ab + (size_t)ch * 8 * 512, &As[0][ch * 1024]);
    }

    int cur = 0;
    for (int tt = 0; tt < NT; ++tt) {
        #pragma unroll
        for (int i = 0; i < 8; ++i) {
            int ch = w * 8 + i;
            gld16(Bb + (size_t)ch * 8 * 512 + tt * 128, &Bs[ch * 1024]);
        }
        SCHEDB();
        int tn = (tt + 1 < NT) ? tt + 1 : tt;
        #pragma unroll
        for (int i = 0; i < 2; ++i) {
            int ch = w * 2 + i;
            gld16(Ab + (size_t)ch * 8 * 512 + tn * 128, &As[cur ^ 1][ch * 1024]);
        }
        SCHEDB();
        asm volatile("s_waitcnt vmcnt(2)" ::: "memory");
        SBAR();

        #pragma unroll
        for (int kk = 0; kk < 2; ++kk) {
            int sl = kk * 4 + l4;
            int slw = (sl ^ (lane & 7)) * 16;
            i32x4 af[4], bf[8];
            #pragma unroll
            for (int m = 0; m < 4; ++m)
                af[m] = *reinterpret_cast<const i32x4*>(&As[cur][(wr * 64 + m * 16 + l15) * 128 + slw]);
            #pragma unroll
            for (int n = 0; n < 8; ++n)
                bf[n] = *reinterpret_cast<const i32x4*>(&Bs[(wc * 128 + n * 16 + l15) * 128 + slw]);
            #pragma unroll
            for (int m = 0; m < 4; ++m)
                #pragma unroll
                for (int n = 0; n < 8; ++n)
                    acc[m][n] = MFMAI8(af[m], bf[n], acc[m][n]);
        }

        SBAR();
        cur ^= 1;
    }

    double cs = (double)s1p[0] * (double)(wmax[0] / 7.0f + 1e-8f);
    double s2v = (double)s2p[0];
    #pragma unroll
    for (int m = 0; m < 4; ++m)
        #pragma unroll
        for (int n = 0; n < 8; ++n)
            #pragma unroll
            for (int j = 0; j < 4; ++j) {
                int row = row0 + wr * 64 + m * 16 + l4 * 4 + j;
                int col = wc * 128 + n * 16 + l15;
                double r = fmax((double)acc[m][n][j] * cs, 0.0) / s2v;
                double qv = fmin(rint(r), 15.0);
                A2[(size_t)row * 512 + col] = (signed char)qv;
                double fr = r - floor(r);
                if (fabs(fr - 0.5) < (double)FLAG_TOL && r < 16.0) {
                    int p = atomicAdd(flagCnt, 1);
                    if (p < FLAG_CAP) flagList[p] = (unsigned)(row * 512 + col);
                }
            }
}

// ---------------- fixups: BLAS-replicating sequential fp32 FMA ----------------

__global__ void k_fixup1(const float* __restrict__ X, const float* __restrict__ W1dq,
                         const float* __restrict__ s1p,
                         const int* __restrict__ flagCnt, const unsigned* __restrict__ flagList,
                         signed char* __restrict__ A1)
{
    int tid = blockIdx.x * blockDim.x + threadIdx.x;
    int nthr = gridDim.x * blockDim.x;
    int n = flagCnt[0];
    if (n > FLAG_CAP) n = FLAG_CAP;
    float s1 = s1p[0];
    for (int i = tid; i < n; i += nthr) {
        unsigned idx = flagList[i];
        int row = (int)(idx >> 9), col = (int)(idx & 511);
        const float* xr = X + (size_t)row * 784;
        const float* wr = W1dq + (size_t)col * 784;
        float acc = 0.f;
        for (int k = 0; k < 784; ++k)
            acc = fmaf(xr[k], wr[k], acc);       // k-ascending, single acc: BLAS order
        float tq = fmaxf(acc, 0.f) / s1;
        float code = fminf(rintf(tq), 15.f);
        A1[(size_t)row * 512 + col] = (signed char)code;
    }
}

__global__ void k_fixup2(const signed char* __restrict__ A1, const float* __restrict__ W2dq,
                         const float* __restrict__ s1p, const float* __restrict__ s2p,
                         const int* __restrict__ flagCnt, const unsigned* __restrict__ flagList,
                         signed char* __restrict__ A2)
{
    int tid = blockIdx.x * blockDim.x + threadIdx.x;
    int nthr = gridDim.x * blockDim.x;
    int n = flagCnt[0];
    if (n > FLAG_CAP) n = FLAG_CAP;
    float s1 = s1p[0], s2 = s2p[0];
    for (int i = tid; i < n; i += nthr) {
        unsigned idx = flagList[i];
        int row = (int)(idx >> 9), col = (int)(idx & 511);
        const signed char* ar = A1 + (size_t)row * 512;
        const float* wr = W2dq + (size_t)col * 512;
        float acc = 0.f;
        for (int k = 0; k < 512; ++k) {
            float adq = (float)ar[k] * s1;       // fp32 dequant, == ref
            acc = fmaf(adq, wr[k], acc);
        }
        float tq = fmaxf(acc, 0.f) / s2;
        float code = fminf(rintf(tq), 15.f);
        A2[(size_t)row * 512 + col] = (signed char)code;
    }
}

// ---------------- GEMM3: int8 [65536,512] @ [16,512]^T -> fp32 logits ----------------
// 512 blocks x 128 rows (2 blocks/CU; was 256 x 256 at 1 block/CU)

__global__ __launch_bounds__(256) void k_gemm3i(
    const signed char* __restrict__ A2, const signed char* __restrict__ Q3,
    const float* __restrict__ wmax, const float* __restrict__ s2p,
    float* __restrict__ Out)
{
    __shared__ __align__(16) signed char As[128][80];   // 64B data + 16B pad
    __shared__ __align__(16) signed char Bs[16][80];

    const int t = threadIdx.x;
    const int row0 = blockIdx.x * 128;
    const int lane = t & 63, wv = t >> 6;

    i32x4 acc[2];
    #pragma unroll
    for (int m = 0; m < 2; ++m) acc[m] = (i32x4){0, 0, 0, 0};

    for (int k0 = 0; k0 < 512; k0 += 64) {
        #pragma unroll
        for (int i = 0; i < 2; ++i) {
            int f = t + 256 * i;
            int r = f >> 2, c = f & 3;
            *reinterpret_cast<uint4*>(&As[r][c * 16]) =
                *reinterpret_cast<const uint4*>(A2 + (size_t)(row0 + r) * 512 + k0 + c * 16);
        }
        if (t < 64) {
            int r = t >> 2, c = t & 3;
            *reinterpret_cast<uint4*>(&Bs[r][c * 16]) =
                *reinterpret_cast<const uint4*>(Q3 + (size_t)r * 512 + k0 + c * 16);
        }
        __syncthreads();

        i32x4 bf = *reinterpret_cast<const i32x4*>(&Bs[lane & 15][(lane >> 4) * 16]);
        #pragma unroll
        for (int m = 0; m < 2; ++m) {
            i32x4 af = *reinterpret_cast<const i32x4*>(&As[wv * 32 + m * 16 + (lane & 15)][(lane >> 4) * 16]);
            acc[m] = MFMAI8(af, bf, acc[m]);
        }
        __syncthreads();
    }

    double cs = (double)s2p[0] * (double)(wmax[0] / 7.0f + 1e-8f);
    #pragma unroll
    for (int m = 0; m < 2; ++m)
        #pragma unroll
        for (int j = 0; j < 4; ++j) {
            int row = row0 + wv * 32 + m * 16 + (lane >> 4) * 4 + j;
            int col = lane & 15;
            if (col < 10)
                Out[(size_t)row * 10 + col] = (float)((double)acc[m][j] * cs);
        }
}

// ---------------- launch ----------------

extern "C" void kernel_launch(void* const* d_in, const int* in_sizes, int n_in,
                              void* d_out, int out_size, void* d_ws, size_t ws_size,
                              hipStream_t stream)
{
    (void)in_sizes; (void)n_in; (void)out_size; (void)ws_size;

    const float* X  = (const float*)d_in[0];
    const float* W1 = (const float*)d_in[1];
    const float* W2 = (const float*)d_in[2];
    const float* W3 = (const float*)d_in[3];
    const float* s1 = (const float*)d_in[4];
    const float* s2 = (const float*)d_in[5];
    float* Out = (float*)d_out;

    char* ws = (char*)d_ws;
    float* maxes     = (float*)ws;
    int*   cnts      = (int*)(ws + 16);
    f16*   q1h       = (f16*)(ws + (size_t)(1u << 20));              // 852992 B
    float* w1dq      = (float*)(ws + (size_t)(2u << 20));            // 1605632 B
    float* w2dq      = (float*)(ws + (size_t)(4u << 20));            // 1048576 B
    signed char* q2i = (signed char*)(ws + (size_t)(6u << 20));      // 262144 B
    signed char* q3i = (signed char*)(ws + (size_t)(6u << 20) + 300000);  // 8192 B
    signed char* a1  = (signed char*)(ws + (size_t)(8u << 20));      // 32 MB
    signed char* a2  = (signed char*)(ws + (size_t)(40u << 20));     // 32 MB
    unsigned* fl1    = (unsigned*)(ws + (size_t)(72u << 20));        // 4 MB
    unsigned* fl2    = (unsigned*)(ws + (size_t)(76u << 20));        // 4 MB

    k_zero<<<1, 64, 0, stream>>>(maxes, cnts);
    k_absmax3<<<520, 256, 0, stream>>>(W1, W2, W3, maxes);
    k_quant_all<<<2720, 256, 0, stream>>>(W1, W2, W3, maxes, q1h, w1dq, q2i, w2dq, q3i);

    k_gemm1W3<<<4096, 256, 0, stream>>>(X, q1h, maxes + 0, s1, a1, cnts + 0, fl1);
    k_fixup1<<<512, 256, 0, stream>>>(X, w1dq, s1, cnts + 0, fl1, a1);
    k_gemm2F<<<512, 512, 0, stream>>>(a1, q2i, maxes + 1, s1, s2, a2, cnts + 1, fl2);
    k_fixup2<<<512, 256, 0, stream>>>(a1, w2dq, s1, s2, cnts + 1, fl2, a2);
    k_gemm3i<<<512, 256, 0, stream>>>(a2, q3i, maxes + 2, s2, Out);
}